// Round 7
// baseline (266.095 us; speedup 1.0000x reference)
//
#include <hip/hip_runtime.h>
#include <cstddef>

typedef unsigned short ushort_t;
typedef __attribute__((ext_vector_type(8))) short sh8;   // 8 x bf16 bits = 4 VGPRs
typedef __attribute__((ext_vector_type(4))) float f4;    // MFMA 16x16x32 C/D
typedef __attribute__((ext_vector_type(4))) unsigned short us4;

static constexpr int Bc = 4, Cc = 512, Nc = 2048, Hc = 8, DKc = 64, O3c = 1536;
static constexpr int BHN = Bc * Hc * Nc;               // 65536
static constexpr int NSPLIT_S = 4;                     // stats i-split
static constexpr float K2 = 0.125f * 1.44269504089f;   // scale * log2(e), folded into q

__device__ __forceinline__ unsigned short f2bf(float f) {
    union { float f; unsigned u; } v; v.f = f;
    unsigned r = v.u + 0x7FFFu + ((v.u >> 16) & 1u);  // RNE
    return (unsigned short)(r >> 16);
}
__device__ __forceinline__ float bf2f(unsigned short b) {
    union { unsigned u; float f; } v; v.u = ((unsigned)b) << 16;
    return v.f;
}
__device__ __forceinline__ unsigned fbits(float f) {
    union { float f; unsigned u; } v; v.f = f; return v.u;
}
__device__ __forceinline__ void gl_lds16(const ushort_t* g, ushort_t* l) {
    __builtin_amdgcn_global_load_lds(
        (const __attribute__((address_space(1))) unsigned int*)g,
        (__attribute__((address_space(3))) unsigned int*)l, 16, 0, 0);
}

// ---------------------------------------------------------------------------
// Prep A: x[b,c,n] fp32 -> xt[b,n,c] bf16
// ---------------------------------------------------------------------------
__global__ __launch_bounds__(256) void xpose_kernel(
    const float* __restrict__ x, ushort_t* __restrict__ xt)
{
    __shared__ float t[32][33];
    const int b = blockIdx.z, n0 = blockIdx.x * 32, c0 = blockIdx.y * 32;
    const int tx = threadIdx.x & 31, ty = threadIdx.x >> 5;
    const float* xb = x + (size_t)b * Cc * Nc;
#pragma unroll
    for (int r = 0; r < 4; ++r)
        t[ty + r * 8][tx] = xb[(size_t)(c0 + ty + r * 8) * Nc + n0 + tx];
    __syncthreads();
    ushort_t* xtb = xt + (size_t)b * Nc * Cc;
#pragma unroll
    for (int r = 0; r < 4; ++r)
        xtb[(size_t)(n0 + ty + r * 8) * Cc + c0 + tx] = f2bf(t[tx][ty + r * 8]);
}

// ---------------------------------------------------------------------------
// Prep B: fp32 -> bf16 bulk convert
// ---------------------------------------------------------------------------
__global__ __launch_bounds__(256) void cvt_kernel(
    const float* __restrict__ s, ushort_t* __restrict__ d, int n4)
{
    int i = blockIdx.x * 256 + threadIdx.x;
    if (i < n4) {
        float4 v = ((const float4*)s)[i];
        us4 o = { f2bf(v.x), f2bf(v.y), f2bf(v.z), f2bf(v.w) };
        ((us4*)d)[i] = o;
    }
}

// ---------------------------------------------------------------------------
// Kernel 1: qkv projection, double-buffered frag prefetch (unroll-2).
// q rows pre-scaled by K2. v waves: C[token][o] -> vT us4. q/k waves:
// C[o][token] -> us4 stores of 4 consecutive d.
// ---------------------------------------------------------------------------
__global__ __launch_bounds__(256, 3) void qkv_kernel(
    const ushort_t* __restrict__ xt, const ushort_t* __restrict__ Wpb,
    const float* __restrict__ bp,
    ushort_t* __restrict__ q, ushort_t* __restrict__ k, ushort_t* __restrict__ vT)
{
    const int tid = threadIdx.x;
    const int wave = tid >> 6, lane = tid & 63, quad = lane >> 4, l15 = lane & 15;
    const int b = blockIdx.z;
    const int m0 = blockIdx.y * 128 + (wave & 1) * 64;   // token base
    const int o0 = blockIdx.x * 128 + (wave >> 1) * 64;  // qkv feature base
    const ushort_t* A  = xt  + ((size_t)b * Nc + m0) * Cc;
    const ushort_t* Bp = Wpb + (size_t)o0 * Cc;

    const int f  = (o0 >> 6) % 3;   // wave-uniform
    const int h  = o0 / 192;
    const int bh = b * Hc + h;

    f4 acc[4][4];
#pragma unroll
    for (int i = 0; i < 4; ++i)
#pragma unroll
        for (int j = 0; j < 4; ++j) acc[i][j] = (f4)0.f;

    sh8 a[4], bb[4], an[4], bn[4];
#pragma unroll
    for (int t = 0; t < 4; ++t) {
        a[t]  = *(const sh8*)&A[(size_t)(t * 16 + l15) * Cc + quad * 8];
        bb[t] = *(const sh8*)&Bp[(size_t)(t * 16 + l15) * Cc + quad * 8];
    }

    if (f == 2) {
        for (int kk = 0; kk < Cc; kk += 64) {
#pragma unroll
            for (int t = 0; t < 4; ++t) {
                an[t] = *(const sh8*)&A[(size_t)(t * 16 + l15) * Cc + kk + 32 + quad * 8];
                bn[t] = *(const sh8*)&Bp[(size_t)(t * 16 + l15) * Cc + kk + 32 + quad * 8];
            }
#pragma unroll
            for (int mi = 0; mi < 4; ++mi)
#pragma unroll
                for (int ni = 0; ni < 4; ++ni)
                    acc[mi][ni] = __builtin_amdgcn_mfma_f32_16x16x32_bf16(
                        a[mi], bb[ni], acc[mi][ni], 0, 0, 0);
            if (kk + 64 < Cc) {
#pragma unroll
                for (int t = 0; t < 4; ++t) {
                    a[t]  = *(const sh8*)&A[(size_t)(t * 16 + l15) * Cc + kk + 64 + quad * 8];
                    bb[t] = *(const sh8*)&Bp[(size_t)(t * 16 + l15) * Cc + kk + 64 + quad * 8];
                }
            }
#pragma unroll
            for (int mi = 0; mi < 4; ++mi)
#pragma unroll
                for (int ni = 0; ni < 4; ++ni)
                    acc[mi][ni] = __builtin_amdgcn_mfma_f32_16x16x32_bf16(
                        an[mi], bn[ni], acc[mi][ni], 0, 0, 0);
        }
#pragma unroll
        for (int ni = 0; ni < 4; ++ni) {
            const int o = o0 + ni * 16 + l15;
            const int d = o & 63;
            const float bias = bp[o];
            ushort_t* dst = vT + ((size_t)bh * DKc + d) * Nc + m0;
#pragma unroll
            for (int mi = 0; mi < 4; ++mi) {
                us4 pk = { f2bf(acc[mi][ni][0] + bias), f2bf(acc[mi][ni][1] + bias),
                           f2bf(acc[mi][ni][2] + bias), f2bf(acc[mi][ni][3] + bias) };
                *(us4*)&dst[mi * 16 + quad * 4] = pk;
            }
        }
    } else {
        for (int kk = 0; kk < Cc; kk += 64) {
#pragma unroll
            for (int t = 0; t < 4; ++t) {
                an[t] = *(const sh8*)&A[(size_t)(t * 16 + l15) * Cc + kk + 32 + quad * 8];
                bn[t] = *(const sh8*)&Bp[(size_t)(t * 16 + l15) * Cc + kk + 32 + quad * 8];
            }
#pragma unroll
            for (int mo = 0; mo < 4; ++mo)
#pragma unroll
                for (int nt = 0; nt < 4; ++nt)
                    acc[mo][nt] = __builtin_amdgcn_mfma_f32_16x16x32_bf16(
                        bb[mo], a[nt], acc[mo][nt], 0, 0, 0);
            if (kk + 64 < Cc) {
#pragma unroll
                for (int t = 0; t < 4; ++t) {
                    a[t]  = *(const sh8*)&A[(size_t)(t * 16 + l15) * Cc + kk + 64 + quad * 8];
                    bb[t] = *(const sh8*)&Bp[(size_t)(t * 16 + l15) * Cc + kk + 64 + quad * 8];
                }
            }
#pragma unroll
            for (int mo = 0; mo < 4; ++mo)
#pragma unroll
                for (int nt = 0; nt < 4; ++nt)
                    acc[mo][nt] = __builtin_amdgcn_mfma_f32_16x16x32_bf16(
                        bn[mo], an[nt], acc[mo][nt], 0, 0, 0);
        }
        const float qs = (f == 0) ? K2 : 1.0f;
        ushort_t* dst = (f == 0 ? q : k) + (size_t)bh * Nc * DKc;
#pragma unroll
        for (int mo = 0; mo < 4; ++mo) {
            const int d0 = mo * 16 + quad * 4;            // 4 consecutive d
            const float4 b4 = *(const float4*)&bp[o0 + d0];
#pragma unroll
            for (int nt = 0; nt < 4; ++nt) {
                const int token = m0 + nt * 16 + l15;
                us4 pk = { f2bf((acc[mo][nt][0] + b4.x) * qs),
                           f2bf((acc[mo][nt][1] + b4.y) * qs),
                           f2bf((acc[mo][nt][2] + b4.z) * qs),
                           f2bf((acc[mo][nt][3] + b4.w) * qs) };
                *(us4*)&dst[(size_t)token * DKc + d0] = pk;
            }
        }
    }
}

// ---------------------------------------------------------------------------
// Kernel 2: partial column sums, 4-way i-split. grid 1024, 4 blocks/CU.
// id = jb*128 + bh*4 + is (XCD-affine in (bh,is)).
// ---------------------------------------------------------------------------
__global__ __launch_bounds__(256, 4) void stats_kernel(
    const ushort_t* __restrict__ q, const ushort_t* __restrict__ k,
    float* __restrict__ spart)
{
    const int tid = threadIdx.x;
    const int wave = tid >> 6, lane = tid & 63, quad = lane >> 4, l15 = lane & 15;
    const int id = blockIdx.x;
    const int jb = id >> 7;
    const int bh = (id >> 2) & 31;
    const int is = id & 3;
    const int j0 = jb * 256 + wave * 64;
    const int ibase = is * (Nc / NSPLIT_S);
    const ushort_t* K = k + ((size_t)bh * Nc + j0) * DKc;
    const ushort_t* Q = q + (size_t)bh * Nc * DKc;

    sh8 aK[4][2];
#pragma unroll
    for (int mj = 0; mj < 4; ++mj)
#pragma unroll
        for (int kk = 0; kk < 2; ++kk)
            aK[mj][kk] = *(const sh8*)&K[(size_t)(mj * 16 + l15) * DKc + kk * 32 + quad * 8];

    float lsum[4][4] = {};
    for (int it = 0; it < Nc / NSPLIT_S; it += 64) {
        const int i0 = ibase + it;
        sh8 bQ[4][2];
#pragma unroll
        for (int ni = 0; ni < 4; ++ni)
#pragma unroll
            for (int kk = 0; kk < 2; ++kk)
                bQ[ni][kk] = *(const sh8*)&Q[(size_t)(i0 + ni * 16 + l15) * DKc + kk * 32 + quad * 8];
#pragma unroll
        for (int mj = 0; mj < 4; ++mj)
#pragma unroll
            for (int ni = 0; ni < 4; ++ni) {
                f4 s = (f4)0.f;
                s = __builtin_amdgcn_mfma_f32_16x16x32_bf16(aK[mj][0], bQ[ni][0], s, 0, 0, 0);
                s = __builtin_amdgcn_mfma_f32_16x16x32_bf16(aK[mj][1], bQ[ni][1], s, 0, 0, 0);
#pragma unroll
                for (int r = 0; r < 4; ++r)
                    lsum[mj][r] += exp2f(s[r]);
            }
    }
#pragma unroll
    for (int mj = 0; mj < 4; ++mj)
#pragma unroll
        for (int r = 0; r < 4; ++r) {
            float v = lsum[mj][r];
            v += __shfl_xor(v, 1); v += __shfl_xor(v, 2);
            v += __shfl_xor(v, 4); v += __shfl_xor(v, 8);
            if (l15 == 0)
                spart[((size_t)is * Bc * Hc + bh) * Nc + j0 + mj * 16 + quad * 4 + r] = v;
        }
}

// vT[bh,d,j] *= 1/sum_is spart[is][bh,j]
__global__ __launch_bounds__(256) void vscale_kernel(
    ushort_t* __restrict__ vT, const float* __restrict__ spart)
{
    int i = blockIdx.x * 256 + threadIdx.x;   // us4 index
    int f = i * 4;
    int row = f >> 11;                        // bh*64 + d
    int j = f & 2047;
    int bh = row >> 6;
    const float* sp = spart + (size_t)bh * Nc + j;
    float4 s0 = *(const float4*)sp;
    float4 s1 = *(const float4*)(sp + BHN);
    float4 s2 = *(const float4*)(sp + 2 * BHN);
    float4 s3 = *(const float4*)(sp + 3 * BHN);
    float4 t = { s0.x + s1.x + s2.x + s3.x, s0.y + s1.y + s2.y + s3.y,
                 s0.z + s1.z + s2.z + s3.z, s0.w + s1.w + s2.w + s3.w };
    us4 v = ((us4*)vT)[i];
    us4 o = { f2bf(bf2f(v[0]) / t.x), f2bf(bf2f(v[1]) / t.y),
              f2bf(bf2f(v[2]) / t.z), f2bf(bf2f(v[3]) / t.w) };
    ((us4*)vT)[i] = o;
}

// ---------------------------------------------------------------------------
// Kernel 3: partial PV. grid 1024; block = 2 i-halves x 2 j-halves of a
// shared 128-j stage; Ps chunked to 64x32 (4 KB/wave) -> LDS 48 KB,
// 3 blocks/CU. Ps half-granule swizzle: write b64 and read b128 both
// bank-uniform (enumerated). jw-pairs combine acc via LDS f32 at the end.
// ---------------------------------------------------------------------------
__global__ __launch_bounds__(256, 3) void apply_kernel(
    const ushort_t* __restrict__ q, const ushort_t* __restrict__ k,
    const ushort_t* __restrict__ vT,
    ushort_t* __restrict__ part0, ushort_t* __restrict__ part1)
{
    __shared__ __align__(16) ushort_t Ks[128 * 64];     // 16 KB
    __shared__ __align__(16) ushort_t Vs[64 * 128];     // 16 KB
    __shared__ __align__(16) ushort_t Ps[4][64 * 32];   // 16 KB total
    const int tid = threadIdx.x;
    const int wave = tid >> 6, lane = tid & 63, quad = lane >> 4, l15 = lane & 15;
    const int iw = wave >> 1, jw = wave & 1;
    const int id = blockIdx.x;
    const int ibk = id >> 6;          // 16 i-blocks of 128
    const int bh = (id & 63) >> 1;
    const int js = id & 1;
    const int b = bh >> 3, h = bh & 7;
    const int i0 = ibk * 128 + iw * 64;
    const int jbase = js * (Nc / 2);
    const ushort_t* Q  = q  + ((size_t)bh * Nc + i0) * DKc;
    const ushort_t* Kb = k  + (size_t)bh * Nc * DKc;
    const ushort_t* Vb = vT + (size_t)bh * DKc * Nc;
    ushort_t* Pw = Ps[wave];
    const int sw  = l15 & 7;
    const int sw2 = (l15 >> 1) & 3;   // Ps swizzle key
    const int jj  = jw * 64;          // this wave's j-half of the stage

    sh8 bQ[4][2];
#pragma unroll
    for (int ni = 0; ni < 4; ++ni)
#pragma unroll
        for (int kk = 0; kk < 2; ++kk)
            bQ[ni][kk] = *(const sh8*)&Q[(size_t)(ni * 16 + l15) * DKc + kk * 32 + quad * 8];

    f4 acc[4][4];
#pragma unroll
    for (int i = 0; i < 4; ++i)
#pragma unroll
        for (int j = 0; j < 4; ++j) acc[i][j] = (f4)0.f;

    int koff[4], voff[4], lbase[4];
#pragma unroll
    for (int c = 0; c < 4; ++c) {
        int g = c * 256 + tid;
        int rk = g >> 3, ck = (g & 7) ^ (rk & 7);
        koff[c] = rk * DKc + ck * 8;
        int rv = g >> 4, cs = g & 15, cn = (cs & 8) | ((cs & 7) ^ (rv & 7));
        voff[c] = rv * Nc + cn * 8;
        lbase[c] = (c * 256 + wave * 64) * 8;
    }

    for (int st = 0; st < 8; ++st) {
        const int j0 = jbase + st * 128;
#pragma unroll
        for (int c = 0; c < 4; ++c) {
            gl_lds16(Kb + (size_t)j0 * DKc + koff[c], Ks + lbase[c]);
            gl_lds16(Vb + voff[c] + j0,               Vs + lbase[c]);
        }
        __syncthreads();

#pragma unroll
        for (int c = 0; c < 2; ++c) {             // 32-j chunks of this wave's half
            // S^T for the chunk
            sh8 aK[2][2];
#pragma unroll
            for (int mj = 0; mj < 2; ++mj)
#pragma unroll
                for (int kk = 0; kk < 2; ++kk)
                    aK[mj][kk] = *(const sh8*)&Ks[(jj + c * 32 + mj * 16 + l15) * 64 +
                                                  (((kk * 4 + quad) ^ sw) << 3)];
#pragma unroll
            for (int ni = 0; ni < 4; ++ni) {
                const int prow = ni * 16 + l15;
#pragma unroll
                for (int mj = 0; mj < 2; ++mj) {
                    f4 s = (f4)0.f;
                    s = __builtin_amdgcn_mfma_f32_16x16x32_bf16(aK[mj][0], bQ[ni][0], s, 0, 0, 0);
                    s = __builtin_amdgcn_mfma_f32_16x16x32_bf16(aK[mj][1], bQ[ni][1], s, 0, 0, 0);
                    unsigned e0 = fbits(exp2f(s[0]));
                    unsigned e1 = fbits(exp2f(s[1]));
                    unsigned e2 = fbits(exp2f(s[2]));
                    unsigned e3 = fbits(exp2f(s[3]));
                    uint2 pk;
                    pk.x = __builtin_amdgcn_perm(e1, e0, 0x07060302u);
                    pk.y = __builtin_amdgcn_perm(e3, e2, 0x07060302u);
                    const int gp = (mj * 2 + (quad >> 1)) ^ sw2;
                    *(uint2*)&Pw[prow * 32 + gp * 8 + (quad & 1) * 4] = pk;
                }
            }
            // PV for the chunk (K=32)
            sh8 aP[4], bV[4];
#pragma unroll
            for (int mi = 0; mi < 4; ++mi)
                aP[mi] = *(const sh8*)&Pw[(mi * 16 + l15) * 32 + ((quad ^ sw2) << 3)];
            const int gg = (jj >> 3) + c * 4 + quad;   // natural Vs granule 0..15
            const int vcg = (gg & 8) | ((gg & 7) ^ sw);
#pragma unroll
            for (int nd = 0; nd < 4; ++nd)
                bV[nd] = *(const sh8*)&Vs[(nd * 16 + l15) * 128 + (vcg << 3)];
#pragma unroll
            for (int mi = 0; mi < 4; ++mi)
#pragma unroll
                for (int nd = 0; nd < 4; ++nd)
                    acc[mi][nd] = __builtin_amdgcn_mfma_f32_16x16x32_bf16(
                        aP[mi], bV[nd], acc[mi][nd], 0, 0, 0);
        }
        __syncthreads();
    }

    // combine jw pairs: jw=1 writes f32 to LDS (aliasing Ks for iw=0, Vs for
    // iw=1; both dead), jw=0 adds and stores the partial.
    float* cb = (float*)(iw == 0 ? (void*)Ks : (void*)Vs);   // 64x64 f32 = 16 KB
    if (jw == 1) {
#pragma unroll
        for (int mi = 0; mi < 4; ++mi)
#pragma unroll
            for (int nd = 0; nd < 4; ++nd)
#pragma unroll
                for (int r = 0; r < 4; ++r)
                    cb[(mi * 16 + quad * 4 + r) * 64 + nd * 16 + l15] = acc[mi][nd][r];
    }
    __syncthreads();
    if (jw == 0) {
        ushort_t* part = js ? part1 : part0;
        ushort_t* dst = part + ((size_t)b * Nc + i0) * Cc + h * DKc;
#pragma unroll
        for (int mi = 0; mi < 4; ++mi)
#pragma unroll
            for (int nd = 0; nd < 4; ++nd)
#pragma unroll
                for (int r = 0; r < 4; ++r) {
                    float v = acc[mi][nd][r] +
                              cb[(mi * 16 + quad * 4 + r) * 64 + nd * 16 + l15];
                    dst[(size_t)(mi * 16 + quad * 4 + r) * Cc + nd * 16 + l15] = f2bf(v);
                }
    }
}

// res (== part1 in-place) = bf16( fp32(part0) + fp32(part1) )
__global__ __launch_bounds__(256) void reduce_kernel(
    const ushort_t* __restrict__ p0, ushort_t* __restrict__ p1res)
{
    int i = blockIdx.x * 256 + threadIdx.x;
    us4 a = ((const us4*)p0)[i];
    us4 b = ((const us4*)p1res)[i];
    us4 o;
#pragma unroll
    for (int j = 0; j < 4; ++j)
        o[j] = f2bf(bf2f(a[j]) + bf2f(b[j]));
    ((us4*)p1res)[i] = o;
}

// ---------------------------------------------------------------------------
// Kernel 4: out = res @ Wo^T + bo + x.  512-thread blocks, 2-way K-split
// with LDS f32 combine -> 16 waves/CU (was 4 at grid 256x1wave-depth).
// ---------------------------------------------------------------------------
__global__ __launch_bounds__(512, 4) void out_kernel(
    const ushort_t* __restrict__ res, const ushort_t* __restrict__ Wob,
    const float* __restrict__ bo, const float* __restrict__ x,
    float* __restrict__ out)
{
    __shared__ float cbuf[4][64 * 64];   // 64 KB
    const int tid = threadIdx.x;
    const int wave = tid >> 6, lane = tid & 63, quad = lane >> 4, l15 = lane & 15;
    const int kw = wave >> 2, mw = (wave >> 1) & 1, cw = wave & 1;
    const int m0  = blockIdx.x * 128 + mw * 64;   // global token (b*N+n)
    const int co0 = blockIdx.y * 128 + cw * 64;
    const ushort_t* A  = res + (size_t)m0 * Cc;
    const ushort_t* Bw = Wob + (size_t)co0 * Cc;

    f4 acc[4][4];
#pragma unroll
    for (int i = 0; i < 4; ++i)
#pragma unroll
        for (int j = 0; j < 4; ++j) acc[i][j] = (f4)0.f;

    const int kbase = kw * (Cc / 2);
    for (int kk = kbase; kk < kbase + Cc / 2; kk += 32) {
        sh8 a[4], bb[4];
#pragma unroll
        for (int mi = 0; mi < 4; ++mi)
            a[mi] = *(const sh8*)&A[(size_t)(mi * 16 + l15) * Cc + kk + quad * 8];
#pragma unroll
        for (int ni = 0; ni < 4; ++ni)
            bb[ni] = *(const sh8*)&Bw[(size_t)(ni * 16 + l15) * Cc + kk + quad * 8];
#pragma unroll
        for (int mi = 0; mi < 4; ++mi)
#pragma unroll
            for (int ni = 0; ni < 4; ++ni)
                acc[mi][ni] = __builtin_amdgcn_mfma_f32_16x16x32_bf16(
                    a[mi], bb[ni], acc[mi][ni], 0, 0, 0);
    }

    float* cb = cbuf[mw * 2 + cw];
    if (kw == 1) {
#pragma unroll
        for (int mi = 0; mi < 4; ++mi)
#pragma unroll
            for (int ni = 0; ni < 4; ++ni)
#pragma unroll
                for (int r = 0; r < 4; ++r)
                    cb[(mi * 16 + quad * 4 + r) * 64 + ni * 16 + l15] = acc[mi][ni][r];
    }
    __syncthreads();
    if (kw == 0) {
        const int b = m0 >> 11;
        const int n_base = m0 & 2047;
#pragma unroll
        for (int ni = 0; ni < 4; ++ni) {
            const int co = co0 + ni * 16 + l15;
            const float bias = bo[co];
#pragma unroll
            for (int mi = 0; mi < 4; ++mi) {
                const int n = n_base + mi * 16 + quad * 4;
                const size_t idx = ((size_t)b * Cc + co) * Nc + n;
                float4 xr = *(const float4*)&x[idx];
                float4 o;
                o.x = acc[mi][ni][0] + cb[(mi * 16 + quad * 4 + 0) * 64 + ni * 16 + l15] + bias + xr.x;
                o.y = acc[mi][ni][1] + cb[(mi * 16 + quad * 4 + 1) * 64 + ni * 16 + l15] + bias + xr.y;
                o.z = acc[mi][ni][2] + cb[(mi * 16 + quad * 4 + 2) * 64 + ni * 16 + l15] + bias + xr.z;
                o.w = acc[mi][ni][3] + cb[(mi * 16 + quad * 4 + 3) * 64 + ni * 16 + l15] + bias + xr.w;
                *(float4*)&out[idx] = o;
            }
        }
    }
}

// ---------------------------------------------------------------------------
extern "C" void kernel_launch(void* const* d_in, const int* in_sizes, int n_in,
                              void* d_out, int out_size, void* d_ws, size_t ws_size,
                              hipStream_t stream)
{
    const float* x  = (const float*)d_in[0];
    const float* Wp = (const float*)d_in[1];
    const float* bp = (const float*)d_in[2];
    const float* Wo = (const float*)d_in[3];
    const float* bo = (const float*)d_in[4];
    float* out = (float*)d_out;

    float* coef  = (float*)d_ws;                              // unused slot
    float* spart = coef + BHN;                                // NSPLIT_S * BHN
    ushort_t* wsb = (ushort_t*)(spart + (size_t)NSPLIT_S * BHN);
    const size_t nE = (size_t)Bc * Nc * Cc;                   // 4,194,304
    ushort_t* xt  = wsb;                 // also part0 (dead after qkv)
    ushort_t* Wpb = xt  + nE;
    ushort_t* Wob = Wpb + (size_t)O3c * Cc;
    ushort_t* qw  = Wob + (size_t)Cc * Cc;
    ushort_t* kw  = qw + nE;
    ushort_t* vT  = kw + nE;
    ushort_t* res = vT + nE;             // also part1

    xpose_kernel<<<dim3(Nc / 32, Cc / 32, Bc), 256, 0, stream>>>(x, xt);
    cvt_kernel<<<dim3((O3c * Cc / 4 + 255) / 256), 256, 0, stream>>>(Wp, Wpb, O3c * Cc / 4);
    cvt_kernel<<<dim3((Cc * Cc / 4 + 255) / 256), 256, 0, stream>>>(Wo, Wob, Cc * Cc / 4);
    qkv_kernel<<<dim3(O3c / 128, Nc / 128, Bc), 256, 0, stream>>>(xt, Wpb, bp, qw, kw, vT);
    stats_kernel<<<dim3(1024), 256, 0, stream>>>(qw, kw, spart);
    vscale_kernel<<<dim3((int)(nE / 4 / 256)), 256, 0, stream>>>(vT, spart);
    apply_kernel<<<dim3(1024), 256, 0, stream>>>(qw, kw, vT, xt, res);
    reduce_kernel<<<dim3((int)(nE / 4 / 256)), 256, 0, stream>>>(xt, res);
    out_kernel<<<dim3(Bc * Nc / 128, Cc / 128), 512, 0, stream>>>(res, Wob, bo, x, out);
}

// Round 8
// 231.036 us; speedup vs baseline: 1.1517x; 1.1517x over previous
//
#include <hip/hip_runtime.h>
#include <cstddef>

typedef unsigned short ushort_t;
typedef __attribute__((ext_vector_type(8))) short sh8;   // 8 x bf16 bits = 4 VGPRs
typedef __attribute__((ext_vector_type(4))) float f4;    // MFMA 16x16x32 C/D
typedef __attribute__((ext_vector_type(4))) unsigned short us4;

static constexpr int Bc = 4, Cc = 512, Nc = 2048, Hc = 8, DKc = 64, O3c = 1536;
static constexpr int BHN = Bc * Hc * Nc;               // 65536
static constexpr int NSPLIT_S = 2;                     // stats i-split
static constexpr float K2 = 0.125f * 1.44269504089f;   // scale * log2(e), folded into q

__device__ __forceinline__ unsigned short f2bf(float f) {
    union { float f; unsigned u; } v; v.f = f;
    unsigned r = v.u + 0x7FFFu + ((v.u >> 16) & 1u);  // RNE
    return (unsigned short)(r >> 16);
}
__device__ __forceinline__ float bf2f(unsigned short b) {
    union { unsigned u; float f; } v; v.u = ((unsigned)b) << 16;
    return v.f;
}
__device__ __forceinline__ float ubf(unsigned u) {
    union { unsigned u; float f; } v; v.u = u; return v.f;
}
// Schraudolph fast 2^s as f32 (stats) — linear mantissa, deficit <=5.7%,
// shared with apply's bf16 version so the softmax ratio cancels the bias.
__device__ __forceinline__ float fexp2(float s) {
    return ubf((unsigned)(int)fmaf(s, 8388608.0f, 1065353216.0f));
}
// same thing, bf16 bit pattern directly (top-16 of the f32 version)
__device__ __forceinline__ int fexp2_bf(float s) {
    return (int)fmaf(s, 128.0f, 16256.5f);
}
__device__ __forceinline__ void gl_lds16(const ushort_t* g, ushort_t* l) {
    __builtin_amdgcn_global_load_lds(
        (const __attribute__((address_space(1))) unsigned int*)g,
        (__attribute__((address_space(3))) unsigned int*)l, 16, 0, 0);
}

// ---------------------------------------------------------------------------
// Prep A: x[b,c,n] fp32 -> xt[b,n,c] bf16
// ---------------------------------------------------------------------------
__global__ __launch_bounds__(256) void xpose_kernel(
    const float* __restrict__ x, ushort_t* __restrict__ xt)
{
    __shared__ float t[32][33];
    const int b = blockIdx.z, n0 = blockIdx.x * 32, c0 = blockIdx.y * 32;
    const int tx = threadIdx.x & 31, ty = threadIdx.x >> 5;
    const float* xb = x + (size_t)b * Cc * Nc;
#pragma unroll
    for (int r = 0; r < 4; ++r)
        t[ty + r * 8][tx] = xb[(size_t)(c0 + ty + r * 8) * Nc + n0 + tx];
    __syncthreads();
    ushort_t* xtb = xt + (size_t)b * Nc * Cc;
#pragma unroll
    for (int r = 0; r < 4; ++r)
        xtb[(size_t)(n0 + ty + r * 8) * Cc + c0 + tx] = f2bf(t[tx][ty + r * 8]);
}

// ---------------------------------------------------------------------------
// Prep B: fp32 -> bf16 bulk convert
// ---------------------------------------------------------------------------
__global__ __launch_bounds__(256) void cvt_kernel(
    const float* __restrict__ s, ushort_t* __restrict__ d, int n4)
{
    int i = blockIdx.x * 256 + threadIdx.x;
    if (i < n4) {
        float4 v = ((const float4*)s)[i];
        us4 o = { f2bf(v.x), f2bf(v.y), f2bf(v.z), f2bf(v.w) };
        ((us4*)d)[i] = o;
    }
}

// ---------------------------------------------------------------------------
// Kernel 1: qkv projection (R6 version). q rows pre-scaled by K2.
// v waves: C[token][o] -> vT us4. q/k waves: C[o][token] -> us4 of 4 consec d.
// ---------------------------------------------------------------------------
__global__ __launch_bounds__(256) void qkv_kernel(
    const ushort_t* __restrict__ xt, const ushort_t* __restrict__ Wpb,
    const float* __restrict__ bp,
    ushort_t* __restrict__ q, ushort_t* __restrict__ k, ushort_t* __restrict__ vT)
{
    const int tid = threadIdx.x;
    const int wave = tid >> 6, lane = tid & 63, quad = lane >> 4, l15 = lane & 15;
    const int b = blockIdx.z;
    const int m0 = blockIdx.y * 128 + (wave & 1) * 64;   // token base
    const int o0 = blockIdx.x * 128 + (wave >> 1) * 64;  // qkv feature base
    const ushort_t* A  = xt  + ((size_t)b * Nc + m0) * Cc;
    const ushort_t* Bp = Wpb + (size_t)o0 * Cc;

    const int f  = (o0 >> 6) % 3;   // wave-uniform
    const int h  = o0 / 192;
    const int bh = b * Hc + h;

    f4 acc[4][4];
#pragma unroll
    for (int i = 0; i < 4; ++i)
#pragma unroll
        for (int j = 0; j < 4; ++j) acc[i][j] = (f4)0.f;

    if (f == 2) {
        // C[token][o]
        for (int kk = 0; kk < Cc; kk += 32) {
            sh8 a[4], bb[4];
#pragma unroll
            for (int mi = 0; mi < 4; ++mi)
                a[mi] = *(const sh8*)&A[(size_t)(mi * 16 + l15) * Cc + kk + quad * 8];
#pragma unroll
            for (int ni = 0; ni < 4; ++ni)
                bb[ni] = *(const sh8*)&Bp[(size_t)(ni * 16 + l15) * Cc + kk + quad * 8];
#pragma unroll
            for (int mi = 0; mi < 4; ++mi)
#pragma unroll
                for (int ni = 0; ni < 4; ++ni)
                    acc[mi][ni] = __builtin_amdgcn_mfma_f32_16x16x32_bf16(
                        a[mi], bb[ni], acc[mi][ni], 0, 0, 0);
        }
#pragma unroll
        for (int ni = 0; ni < 4; ++ni) {
            const int o = o0 + ni * 16 + l15;
            const int d = o & 63;
            const float bias = bp[o];
            ushort_t* dst = vT + ((size_t)bh * DKc + d) * Nc + m0;
#pragma unroll
            for (int mi = 0; mi < 4; ++mi) {
                us4 pk = { f2bf(acc[mi][ni][0] + bias), f2bf(acc[mi][ni][1] + bias),
                           f2bf(acc[mi][ni][2] + bias), f2bf(acc[mi][ni][3] + bias) };
                *(us4*)&dst[mi * 16 + quad * 4] = pk;
            }
        }
    } else {
        // C[o][token]: A = Wp rows, B = xt rows (same loads, swapped mfma)
        for (int kk = 0; kk < Cc; kk += 32) {
            sh8 a[4], bb[4];
#pragma unroll
            for (int mi = 0; mi < 4; ++mi)
                a[mi] = *(const sh8*)&A[(size_t)(mi * 16 + l15) * Cc + kk + quad * 8];
#pragma unroll
            for (int ni = 0; ni < 4; ++ni)
                bb[ni] = *(const sh8*)&Bp[(size_t)(ni * 16 + l15) * Cc + kk + quad * 8];
#pragma unroll
            for (int mo = 0; mo < 4; ++mo)
#pragma unroll
                for (int nt = 0; nt < 4; ++nt)
                    acc[mo][nt] = __builtin_amdgcn_mfma_f32_16x16x32_bf16(
                        bb[mo], a[nt], acc[mo][nt], 0, 0, 0);
        }
        const float qs = (f == 0) ? K2 : 1.0f;
        ushort_t* dst = (f == 0 ? q : k) + (size_t)bh * Nc * DKc;
#pragma unroll
        for (int mo = 0; mo < 4; ++mo) {
            const int d0 = mo * 16 + quad * 4;            // 4 consecutive d
            const float4 b4 = *(const float4*)&bp[o0 + d0];
#pragma unroll
            for (int nt = 0; nt < 4; ++nt) {
                const int token = m0 + nt * 16 + l15;
                us4 pk = { f2bf((acc[mo][nt][0] + b4.x) * qs),
                           f2bf((acc[mo][nt][1] + b4.y) * qs),
                           f2bf((acc[mo][nt][2] + b4.z) * qs),
                           f2bf((acc[mo][nt][3] + b4.w) * qs) };
                *(us4*)&dst[(size_t)token * DKc + d0] = pk;
            }
        }
    }
}

// ---------------------------------------------------------------------------
// Kernel 2: partial column sums with fast exp2. 1D grid 512, XCD-swizzled.
// ---------------------------------------------------------------------------
__global__ __launch_bounds__(256, 2) void stats_kernel(
    const ushort_t* __restrict__ q, const ushort_t* __restrict__ k,
    float* __restrict__ spart)
{
    const int tid = threadIdx.x;
    const int wave = tid >> 6, lane = tid & 63, quad = lane >> 4, l15 = lane & 15;
    const int id = blockIdx.x;
    const int jb = id >> 6;
    const int bh = (id & 63) >> 1;
    const int js = id & 1;
    const int j0 = jb * 256 + wave * 64;
    const int ibase = js * (Nc / NSPLIT_S);
    const ushort_t* K = k + ((size_t)bh * Nc + j0) * DKc;
    const ushort_t* Q = q + (size_t)bh * Nc * DKc;

    sh8 aK[4][2];
#pragma unroll
    for (int mj = 0; mj < 4; ++mj)
#pragma unroll
        for (int kk = 0; kk < 2; ++kk)
            aK[mj][kk] = *(const sh8*)&K[(size_t)(mj * 16 + l15) * DKc + kk * 32 + quad * 8];

    float lsum[4][4] = {};
    for (int it = 0; it < Nc / NSPLIT_S; it += 64) {
        const int i0 = ibase + it;
        sh8 bQ[4][2];
#pragma unroll
        for (int ni = 0; ni < 4; ++ni)
#pragma unroll
            for (int kk = 0; kk < 2; ++kk)
                bQ[ni][kk] = *(const sh8*)&Q[(size_t)(i0 + ni * 16 + l15) * DKc + kk * 32 + quad * 8];
#pragma unroll
        for (int mj = 0; mj < 4; ++mj)
#pragma unroll
            for (int ni = 0; ni < 4; ++ni) {
                f4 s = (f4)0.f;
                s = __builtin_amdgcn_mfma_f32_16x16x32_bf16(aK[mj][0], bQ[ni][0], s, 0, 0, 0);
                s = __builtin_amdgcn_mfma_f32_16x16x32_bf16(aK[mj][1], bQ[ni][1], s, 0, 0, 0);
#pragma unroll
                for (int r = 0; r < 4; ++r)
                    lsum[mj][r] += fexp2(s[r]);
            }
    }
#pragma unroll
    for (int mj = 0; mj < 4; ++mj)
#pragma unroll
        for (int r = 0; r < 4; ++r) {
            float v = lsum[mj][r];
            v += __shfl_xor(v, 1); v += __shfl_xor(v, 2);
            v += __shfl_xor(v, 4); v += __shfl_xor(v, 8);
            if (l15 == 0)
                spart[((size_t)js * Bc * Hc + bh) * Nc + j0 + mj * 16 + quad * 4 + r] = v;
        }
}

// vT[bh,d,j] *= 1/(spart0+spart1)[bh,j]
__global__ __launch_bounds__(256) void vscale_kernel(
    ushort_t* __restrict__ vT, const float* __restrict__ spart)
{
    int i = blockIdx.x * 256 + threadIdx.x;   // us4 index
    int f = i * 4;
    int row = f >> 11;                        // bh*64 + d
    int j = f & 2047;
    int bh = row >> 6;
    const float* sp = spart + (size_t)bh * Nc + j;
    float4 s0 = *(const float4*)sp;
    float4 s1 = *(const float4*)(sp + BHN);
    us4 v = ((us4*)vT)[i];
    us4 o = { f2bf(bf2f(v[0]) / (s0.x + s1.x)), f2bf(bf2f(v[1]) / (s0.y + s1.y)),
              f2bf(bf2f(v[2]) / (s0.z + s1.z)), f2bf(bf2f(v[3]) / (s0.w + s1.w)) };
    ((us4*)vT)[i] = o;
}

// ---------------------------------------------------------------------------
// Kernel 3: partial PV (R6 structure) with fast bf16 exp2.
// ---------------------------------------------------------------------------
__global__ __launch_bounds__(256, 2) void apply_kernel(
    const ushort_t* __restrict__ q, const ushort_t* __restrict__ k,
    const ushort_t* __restrict__ vT,
    ushort_t* __restrict__ part0, ushort_t* __restrict__ part1)
{
    __shared__ __align__(16) ushort_t Ks[128 * 64];     // 16 KB
    __shared__ __align__(16) ushort_t Vs[64 * 128];     // 16 KB
    __shared__ __align__(16) ushort_t Ps[4][64 * 64];   // 32 KB per-wave
    const int tid = threadIdx.x;
    const int wave = tid >> 6, lane = tid & 63, quad = lane >> 4, l15 = lane & 15;
    const int id = blockIdx.x;
    const int ibk = id >> 6;
    const int bh = (id & 63) >> 1;
    const int js = id & 1;
    const int b = bh >> 3, h = bh & 7;
    const int i0 = ibk * 256 + wave * 64;
    const int jbase = js * (Nc / 2);
    const ushort_t* Q  = q  + ((size_t)bh * Nc + i0) * DKc;
    const ushort_t* Kb = k  + (size_t)bh * Nc * DKc;
    const ushort_t* Vb = vT + (size_t)bh * DKc * Nc;
    ushort_t* Pw = Ps[wave];
    const int sw = l15 & 7;
    const int hb = (l15 >> 3) & 1;

    sh8 bQ[4][2];
#pragma unroll
    for (int ni = 0; ni < 4; ++ni)
#pragma unroll
        for (int kk = 0; kk < 2; ++kk)
            bQ[ni][kk] = *(const sh8*)&Q[(size_t)(ni * 16 + l15) * DKc + kk * 32 + quad * 8];

    f4 acc[4][4];
#pragma unroll
    for (int i = 0; i < 4; ++i)
#pragma unroll
        for (int j = 0; j < 4; ++j) acc[i][j] = (f4)0.f;

    int koff[4], voff[4], lbase[4];
#pragma unroll
    for (int c = 0; c < 4; ++c) {
        int g = c * 256 + tid;
        int rk = g >> 3, ck = (g & 7) ^ (rk & 7);
        koff[c] = rk * DKc + ck * 8;
        int rv = g >> 4, cs = g & 15, cn = (cs & 8) | ((cs & 7) ^ (rv & 7));
        voff[c] = rv * Nc + cn * 8;
        lbase[c] = (c * 256 + wave * 64) * 8;
    }

    for (int st = 0; st < 8; ++st) {
        const int j0 = jbase + st * 128;
#pragma unroll
        for (int c = 0; c < 4; ++c) {
            gl_lds16(Kb + (size_t)j0 * DKc + koff[c], Ks + lbase[c]);
            gl_lds16(Vb + voff[c] + j0,               Vs + lbase[c]);
        }
        __syncthreads();

#pragma unroll
        for (int jj = 0; jj < 128; jj += 64) {
            sh8 aK[4][2];
#pragma unroll
            for (int mj = 0; mj < 4; ++mj)
#pragma unroll
                for (int kk = 0; kk < 2; ++kk)
                    aK[mj][kk] = *(const sh8*)&Ks[(jj + mj * 16 + l15) * 64 +
                                                  (((kk * 4 + quad) ^ sw) << 3)];
#pragma unroll
            for (int ni = 0; ni < 4; ++ni) {
                const int prow = ni * 16 + l15;
#pragma unroll
                for (int mj = 0; mj < 4; ++mj) {
                    f4 s = (f4)0.f;
                    s = __builtin_amdgcn_mfma_f32_16x16x32_bf16(aK[mj][0], bQ[ni][0], s, 0, 0, 0);
                    s = __builtin_amdgcn_mfma_f32_16x16x32_bf16(aK[mj][1], bQ[ni][1], s, 0, 0, 0);
                    const int e0 = fexp2_bf(s[0]);
                    const int e1 = fexp2_bf(s[1]);
                    const int e2 = fexp2_bf(s[2]);
                    const int e3 = fexp2_bf(s[3]);
                    uint2 pk;
                    pk.x = __builtin_amdgcn_perm((unsigned)e1, (unsigned)e0, 0x05040100u);
                    pk.y = __builtin_amdgcn_perm((unsigned)e3, (unsigned)e2, 0x05040100u);
                    const int off = prow * 64 + ((((mj * 2 + (quad >> 1)) ^ sw)) << 3)
                                  + (((quad & 1) ^ hb) << 2);
                    *(uint2*)&Pw[off] = pk;
                }
            }
#pragma unroll
            for (int kk = 0; kk < 2; ++kk) {
                const int cgk = (((kk * 4 + quad) ^ sw)) << 3;
                const int h0 = hb << 2, h1 = 4 - h0;
                sh8 aP[4], bV[4];
#pragma unroll
                for (int mi = 0; mi < 4; ++mi) {
                    union { sh8 s8; uint2 u[2]; } t;
                    const int rb = (mi * 16 + l15) * 64 + cgk;
                    t.u[0] = *(const uint2*)&Pw[rb + h0];
                    t.u[1] = *(const uint2*)&Pw[rb + h1];
                    aP[mi] = t.s8;
                }
                const int gnat = (jj >> 3) + kk * 4 + quad;
                const int vcg = ((gnat & 8) | ((gnat & 7) ^ sw)) << 3;
#pragma unroll
                for (int nd = 0; nd < 4; ++nd)
                    bV[nd] = *(const sh8*)&Vs[(nd * 16 + l15) * 128 + vcg];
#pragma unroll
                for (int mi = 0; mi < 4; ++mi)
#pragma unroll
                    for (int nd = 0; nd < 4; ++nd)
                        acc[mi][nd] = __builtin_amdgcn_mfma_f32_16x16x32_bf16(
                            aP[mi], bV[nd], acc[mi][nd], 0, 0, 0);
            }
        }
        __syncthreads();
    }

    ushort_t* part = js ? part1 : part0;
    ushort_t* dst = part + ((size_t)b * Nc + i0) * Cc + h * DKc;
#pragma unroll
    for (int mi = 0; mi < 4; ++mi)
#pragma unroll
        for (int nd = 0; nd < 4; ++nd)
#pragma unroll
            for (int r = 0; r < 4; ++r)
                dst[(size_t)(mi * 16 + quad * 4 + r) * Cc + nd * 16 + l15] =
                    f2bf(acc[mi][nd][r]);
}

// res (== part1 in-place) = bf16( fp32(part0) + fp32(part1) )
__global__ __launch_bounds__(256) void reduce_kernel(
    const ushort_t* __restrict__ p0, ushort_t* __restrict__ p1res)
{
    int i = blockIdx.x * 256 + threadIdx.x;
    us4 a = ((const us4*)p0)[i];
    us4 b = ((const us4*)p1res)[i];
    us4 o;
#pragma unroll
    for (int j = 0; j < 4; ++j)
        o[j] = f2bf(bf2f(a[j]) + bf2f(b[j]));
    ((us4*)p1res)[i] = o;
}

// ---------------------------------------------------------------------------
// Kernel 4: out[b,co,n] = res @ Wo^T + bo + x  (R6 version)
// ---------------------------------------------------------------------------
__global__ __launch_bounds__(256) void out_kernel(
    const ushort_t* __restrict__ res, const ushort_t* __restrict__ Wob,
    const float* __restrict__ bo, const float* __restrict__ x,
    float* __restrict__ out)
{
    const int tid = threadIdx.x;
    const int wave = tid >> 6, lane = tid & 63, quad = lane >> 4, l15 = lane & 15;
    const int m0  = blockIdx.x * 128 + (wave & 1) * 64;
    const int co0 = blockIdx.y * 128 + (wave >> 1) * 64;
    const ushort_t* A  = res + (size_t)m0 * Cc;
    const ushort_t* Bw = Wob + (size_t)co0 * Cc;

    f4 acc[4][4];
#pragma unroll
    for (int i = 0; i < 4; ++i)
#pragma unroll
        for (int j = 0; j < 4; ++j) acc[i][j] = (f4)0.f;

    for (int kk = 0; kk < Cc; kk += 32) {
        sh8 a[4], bb[4];
#pragma unroll
        for (int mi = 0; mi < 4; ++mi)
            a[mi] = *(const sh8*)&A[(size_t)(mi * 16 + l15) * Cc + kk + quad * 8];
#pragma unroll
        for (int ni = 0; ni < 4; ++ni)
            bb[ni] = *(const sh8*)&Bw[(size_t)(ni * 16 + l15) * Cc + kk + quad * 8];
#pragma unroll
        for (int mi = 0; mi < 4; ++mi)
#pragma unroll
            for (int ni = 0; ni < 4; ++ni)
                acc[mi][ni] = __builtin_amdgcn_mfma_f32_16x16x32_bf16(
                    a[mi], bb[ni], acc[mi][ni], 0, 0, 0);
    }

    const int b = m0 >> 11;
    const int n_base = m0 & 2047;
#pragma unroll
    for (int ni = 0; ni < 4; ++ni) {
        const int co = co0 + ni * 16 + l15;
        const float bias = bo[co];
#pragma unroll
        for (int mi = 0; mi < 4; ++mi) {
            const int n = n_base + mi * 16 + quad * 4;
            const size_t idx = ((size_t)b * Cc + co) * Nc + n;
            float4 xr = *(const float4*)&x[idx];
            float4 o;
            o.x = acc[mi][ni][0] + bias + xr.x;
            o.y = acc[mi][ni][1] + bias + xr.y;
            o.z = acc[mi][ni][2] + bias + xr.z;
            o.w = acc[mi][ni][3] + bias + xr.w;
            *(float4*)&out[idx] = o;
        }
    }
}

// ---------------------------------------------------------------------------
extern "C" void kernel_launch(void* const* d_in, const int* in_sizes, int n_in,
                              void* d_out, int out_size, void* d_ws, size_t ws_size,
                              hipStream_t stream)
{
    const float* x  = (const float*)d_in[0];
    const float* Wp = (const float*)d_in[1];
    const float* bp = (const float*)d_in[2];
    const float* Wo = (const float*)d_in[3];
    const float* bo = (const float*)d_in[4];
    float* out = (float*)d_out;

    float* coef  = (float*)d_ws;                              // unused slot
    float* spart = coef + BHN;                                // NSPLIT_S * BHN
    ushort_t* wsb = (ushort_t*)(spart + (size_t)NSPLIT_S * BHN);
    const size_t nE = (size_t)Bc * Nc * Cc;                   // 4,194,304
    ushort_t* xt  = wsb;                 // also part0 (dead after qkv)
    ushort_t* Wpb = xt  + nE;
    ushort_t* Wob = Wpb + (size_t)O3c * Cc;
    ushort_t* qw  = Wob + (size_t)Cc * Cc;
    ushort_t* kw  = qw + nE;
    ushort_t* vT  = kw + nE;
    ushort_t* res = vT + nE;             // also part1

    xpose_kernel<<<dim3(Nc / 32, Cc / 32, Bc), 256, 0, stream>>>(x, xt);
    cvt_kernel<<<dim3((O3c * Cc / 4 + 255) / 256), 256, 0, stream>>>(Wp, Wpb, O3c * Cc / 4);
    cvt_kernel<<<dim3((Cc * Cc / 4 + 255) / 256), 256, 0, stream>>>(Wo, Wob, Cc * Cc / 4);
    qkv_kernel<<<dim3(O3c / 128, Nc / 128, Bc), 256, 0, stream>>>(xt, Wpb, bp, qw, kw, vT);
    stats_kernel<<<dim3(512), 256, 0, stream>>>(qw, kw, spart);
    vscale_kernel<<<dim3((int)(nE / 4 / 256)), 256, 0, stream>>>(vT, spart);
    apply_kernel<<<dim3(512), 256, 0, stream>>>(qw, kw, vT, xt, res);
    reduce_kernel<<<dim3((int)(nE / 4 / 256)), 256, 0, stream>>>(xt, res);
    out_kernel<<<dim3(Bc * Nc / 128, Cc / 128), 256, 0, stream>>>(res, Wob, bo, x, out);
}

// Round 9
// 202.593 us; speedup vs baseline: 1.3135x; 1.1404x over previous
//
#include <hip/hip_runtime.h>
#include <cstddef>

typedef unsigned short ushort_t;
typedef __attribute__((ext_vector_type(8))) short sh8;   // 8 x bf16 bits = 4 VGPRs
typedef __attribute__((ext_vector_type(4))) float f4;    // MFMA 16x16x32 C/D
typedef __attribute__((ext_vector_type(4))) unsigned short us4;

static constexpr int Bc = 4, Cc = 512, Nc = 2048, Hc = 8, DKc = 64, O3c = 1536;
static constexpr int BHN = Bc * Hc * Nc;               // 65536
static constexpr int NSPLIT_S = 2;                     // stats i-split
static constexpr float K2 = 0.125f * 1.44269504089f;   // scale * log2(e), folded into q

__device__ __forceinline__ unsigned short f2bf(float f) {
    union { float f; unsigned u; } v; v.f = f;
    unsigned r = v.u + 0x7FFFu + ((v.u >> 16) & 1u);  // RNE
    return (unsigned short)(r >> 16);
}
__device__ __forceinline__ float bf2f(unsigned short b) {
    union { unsigned u; float f; } v; v.u = ((unsigned)b) << 16;
    return v.f;
}
__device__ __forceinline__ float ubf(unsigned u) {
    union { unsigned u; float f; } v; v.u = u; return v.f;
}
// Schraudolph fast 2^s (linear mantissa, deficit <=5.7%) — used in BOTH
// stats (denominator) and apply (numerator) so the softmax ratio cancels.
__device__ __forceinline__ float fexp2(float s) {
    return ubf((unsigned)(int)fmaf(s, 8388608.0f, 1065353216.0f));
}
__device__ __forceinline__ int fexp2_bf(float s) {
    return (int)fmaf(s, 128.0f, 16256.5f);
}
__device__ __forceinline__ void gl_lds16(const ushort_t* g, ushort_t* l) {
    __builtin_amdgcn_global_load_lds(
        (const __attribute__((address_space(1))) unsigned int*)g,
        (__attribute__((address_space(3))) unsigned int*)l, 16, 0, 0);
}

// ---------------------------------------------------------------------------
// Prep A: x[b,c,n] fp32 -> xt[b,n,c] bf16
// ---------------------------------------------------------------------------
__global__ __launch_bounds__(256) void xpose_kernel(
    const float* __restrict__ x, ushort_t* __restrict__ xt)
{
    __shared__ float t[32][33];
    const int b = blockIdx.z, n0 = blockIdx.x * 32, c0 = blockIdx.y * 32;
    const int tx = threadIdx.x & 31, ty = threadIdx.x >> 5;
    const float* xb = x + (size_t)b * Cc * Nc;
#pragma unroll
    for (int r = 0; r < 4; ++r)
        t[ty + r * 8][tx] = xb[(size_t)(c0 + ty + r * 8) * Nc + n0 + tx];
    __syncthreads();
    ushort_t* xtb = xt + (size_t)b * Nc * Cc;
#pragma unroll
    for (int r = 0; r < 4; ++r)
        xtb[(size_t)(n0 + ty + r * 8) * Cc + c0 + tx] = f2bf(t[tx][ty + r * 8]);
}

// ---------------------------------------------------------------------------
// Prep B: fp32 -> bf16 bulk convert
// ---------------------------------------------------------------------------
__global__ __launch_bounds__(256) void cvt_kernel(
    const float* __restrict__ s, ushort_t* __restrict__ d, int n4)
{
    int i = blockIdx.x * 256 + threadIdx.x;
    if (i < n4) {
        float4 v = ((const float4*)s)[i];
        us4 o = { f2bf(v.x), f2bf(v.y), f2bf(v.z), f2bf(v.w) };
        ((us4*)d)[i] = o;
    }
}

// ---------------------------------------------------------------------------
// Kernel 1: qkv projection, m97-style LDS-staged GEMM.
// Block tile 128 tokens x 128 o; K-loop 8 stages of 64, A/B staged via
// global_load_lds width-16 into granule-XOR-swizzled LDS (conflict-free
// ds_read_b128 frags). Wave-uniform f selects operand order:
// v waves C[token][o] -> vT us4; q/k waves C[o][token] -> us4 of 4 consec d.
// ---------------------------------------------------------------------------
__global__ __launch_bounds__(256, 2) void qkv_kernel(
    const ushort_t* __restrict__ xt, const ushort_t* __restrict__ Wpb,
    const float* __restrict__ bp,
    ushort_t* __restrict__ q, ushort_t* __restrict__ k, ushort_t* __restrict__ vT)
{
    __shared__ __align__(16) ushort_t As[128 * 64];   // 16 KB
    __shared__ __align__(16) ushort_t Bs[128 * 64];   // 16 KB
    const int tid = threadIdx.x;
    const int wave = tid >> 6, lane = tid & 63, quad = lane >> 4, l15 = lane & 15;
    const int b = blockIdx.z;
    const int t0  = blockIdx.y * 128;              // block token base
    const int o0b = blockIdx.x * 128;              // block o base
    const int wt = wave & 1, wo = wave >> 1;
    const int m0 = t0 + wt * 64;                   // wave token base
    const int o0 = o0b + wo * 64;                  // wave o base
    const ushort_t* Ag = xt  + ((size_t)b * Nc + t0) * Cc;
    const ushort_t* Bg = Wpb + (size_t)o0b * Cc;
    const int f  = (o0 >> 6) % 3;                  // wave-uniform
    const int h  = o0 / 192;
    const int bh = b * Hc + h;
    const int sw = l15 & 7;

    f4 acc[4][4];
#pragma unroll
    for (int i = 0; i < 4; ++i)
#pragma unroll
        for (int j = 0; j < 4; ++j) acc[i][j] = (f4)0.f;

    // staging: LDS slot g holds natural granule ((g&7)^(row&7)) of row g>>3
    int goff[4], lbase[4];
#pragma unroll
    for (int c = 0; c < 4; ++c) {
        int g = c * 256 + tid;
        int r = g >> 3, cn = (g & 7) ^ (r & 7);
        goff[c]  = r * Cc + cn * 8;
        lbase[c] = (c * 256 + wave * 64) * 8;
    }

    for (int st = 0; st < 8; ++st) {
        const int k0 = st * 64;
#pragma unroll
        for (int c = 0; c < 4; ++c) {
            gl_lds16(Ag + k0 + goff[c], As + lbase[c]);
            gl_lds16(Bg + k0 + goff[c], Bs + lbase[c]);
        }
        __syncthreads();

        sh8 aA[4][2], bB[4][2];
#pragma unroll
        for (int mi = 0; mi < 4; ++mi)
#pragma unroll
            for (int kk = 0; kk < 2; ++kk)
                aA[mi][kk] = *(const sh8*)&As[(wt * 64 + mi * 16 + l15) * 64 +
                                              (((kk * 4 + quad) ^ sw) << 3)];
#pragma unroll
        for (int ni = 0; ni < 4; ++ni)
#pragma unroll
            for (int kk = 0; kk < 2; ++kk)
                bB[ni][kk] = *(const sh8*)&Bs[(wo * 64 + ni * 16 + l15) * 64 +
                                              (((kk * 4 + quad) ^ sw) << 3)];
        if (f == 2) {
#pragma unroll
            for (int kk = 0; kk < 2; ++kk)
#pragma unroll
                for (int mi = 0; mi < 4; ++mi)
#pragma unroll
                    for (int ni = 0; ni < 4; ++ni)
                        acc[mi][ni] = __builtin_amdgcn_mfma_f32_16x16x32_bf16(
                            aA[mi][kk], bB[ni][kk], acc[mi][ni], 0, 0, 0);
        } else {
#pragma unroll
            for (int kk = 0; kk < 2; ++kk)
#pragma unroll
                for (int mo = 0; mo < 4; ++mo)
#pragma unroll
                    for (int nt = 0; nt < 4; ++nt)
                        acc[mo][nt] = __builtin_amdgcn_mfma_f32_16x16x32_bf16(
                            bB[mo][kk], aA[nt][kk], acc[mo][nt], 0, 0, 0);
        }
        __syncthreads();
    }

    if (f == 2) {
#pragma unroll
        for (int ni = 0; ni < 4; ++ni) {
            const int o = o0 + ni * 16 + l15;
            const int d = o & 63;
            const float bias = bp[o];
            ushort_t* dst = vT + ((size_t)bh * DKc + d) * Nc + m0;
#pragma unroll
            for (int mi = 0; mi < 4; ++mi) {
                us4 pk = { f2bf(acc[mi][ni][0] + bias), f2bf(acc[mi][ni][1] + bias),
                           f2bf(acc[mi][ni][2] + bias), f2bf(acc[mi][ni][3] + bias) };
                *(us4*)&dst[mi * 16 + quad * 4] = pk;
            }
        }
    } else {
        const float qs = (f == 0) ? K2 : 1.0f;
        ushort_t* dst = (f == 0 ? q : k) + (size_t)bh * Nc * DKc;
#pragma unroll
        for (int mo = 0; mo < 4; ++mo) {
            const int d0 = mo * 16 + quad * 4;            // 4 consecutive d
            const float4 b4 = *(const float4*)&bp[o0 + d0];
#pragma unroll
            for (int nt = 0; nt < 4; ++nt) {
                const int token = m0 + nt * 16 + l15;
                us4 pk = { f2bf((acc[mo][nt][0] + b4.x) * qs),
                           f2bf((acc[mo][nt][1] + b4.y) * qs),
                           f2bf((acc[mo][nt][2] + b4.z) * qs),
                           f2bf((acc[mo][nt][3] + b4.w) * qs) };
                *(us4*)&dst[(size_t)token * DKc + d0] = pk;
            }
        }
    }
}

// ---------------------------------------------------------------------------
// Kernel 2: partial column sums with fast exp2. 1D grid 512, XCD-swizzled.
// ---------------------------------------------------------------------------
__global__ __launch_bounds__(256, 2) void stats_kernel(
    const ushort_t* __restrict__ q, const ushort_t* __restrict__ k,
    float* __restrict__ spart)
{
    const int tid = threadIdx.x;
    const int wave = tid >> 6, lane = tid & 63, quad = lane >> 4, l15 = lane & 15;
    const int id = blockIdx.x;
    const int jb = id >> 6;
    const int bh = (id & 63) >> 1;
    const int js = id & 1;
    const int j0 = jb * 256 + wave * 64;
    const int ibase = js * (Nc / NSPLIT_S);
    const ushort_t* K = k + ((size_t)bh * Nc + j0) * DKc;
    const ushort_t* Q = q + (size_t)bh * Nc * DKc;

    sh8 aK[4][2];
#pragma unroll
    for (int mj = 0; mj < 4; ++mj)
#pragma unroll
        for (int kk = 0; kk < 2; ++kk)
            aK[mj][kk] = *(const sh8*)&K[(size_t)(mj * 16 + l15) * DKc + kk * 32 + quad * 8];

    float lsum[4][4] = {};
    for (int it = 0; it < Nc / NSPLIT_S; it += 64) {
        const int i0 = ibase + it;
        sh8 bQ[4][2];
#pragma unroll
        for (int ni = 0; ni < 4; ++ni)
#pragma unroll
            for (int kk = 0; kk < 2; ++kk)
                bQ[ni][kk] = *(const sh8*)&Q[(size_t)(i0 + ni * 16 + l15) * DKc + kk * 32 + quad * 8];
#pragma unroll
        for (int mj = 0; mj < 4; ++mj)
#pragma unroll
            for (int ni = 0; ni < 4; ++ni) {
                f4 s = (f4)0.f;
                s = __builtin_amdgcn_mfma_f32_16x16x32_bf16(aK[mj][0], bQ[ni][0], s, 0, 0, 0);
                s = __builtin_amdgcn_mfma_f32_16x16x32_bf16(aK[mj][1], bQ[ni][1], s, 0, 0, 0);
#pragma unroll
                for (int r = 0; r < 4; ++r)
                    lsum[mj][r] += fexp2(s[r]);
            }
    }
#pragma unroll
    for (int mj = 0; mj < 4; ++mj)
#pragma unroll
        for (int r = 0; r < 4; ++r) {
            float v = lsum[mj][r];
            v += __shfl_xor(v, 1); v += __shfl_xor(v, 2);
            v += __shfl_xor(v, 4); v += __shfl_xor(v, 8);
            if (l15 == 0)
                spart[((size_t)js * Bc * Hc + bh) * Nc + j0 + mj * 16 + quad * 4 + r] = v;
        }
}

// vT[bh,d,j] *= 1/(spart0+spart1)[bh,j]
__global__ __launch_bounds__(256) void vscale_kernel(
    ushort_t* __restrict__ vT, const float* __restrict__ spart)
{
    int i = blockIdx.x * 256 + threadIdx.x;   // us4 index
    int f = i * 4;
    int row = f >> 11;                        // bh*64 + d
    int j = f & 2047;
    int bh = row >> 6;
    const float* sp = spart + (size_t)bh * Nc + j;
    float4 s0 = *(const float4*)sp;
    float4 s1 = *(const float4*)(sp + BHN);
    us4 v = ((us4*)vT)[i];
    us4 o = { f2bf(bf2f(v[0]) / (s0.x + s1.x)), f2bf(bf2f(v[1]) / (s0.y + s1.y)),
              f2bf(bf2f(v[2]) / (s0.z + s1.z)), f2bf(bf2f(v[3]) / (s0.w + s1.w)) };
    ((us4*)vT)[i] = o;
}

// ---------------------------------------------------------------------------
// Kernel 3: partial PV (R6 structure) with fast bf16 exp2.
// ---------------------------------------------------------------------------
__global__ __launch_bounds__(256, 2) void apply_kernel(
    const ushort_t* __restrict__ q, const ushort_t* __restrict__ k,
    const ushort_t* __restrict__ vT,
    ushort_t* __restrict__ part0, ushort_t* __restrict__ part1)
{
    __shared__ __align__(16) ushort_t Ks[128 * 64];     // 16 KB
    __shared__ __align__(16) ushort_t Vs[64 * 128];     // 16 KB
    __shared__ __align__(16) ushort_t Ps[4][64 * 64];   // 32 KB per-wave
    const int tid = threadIdx.x;
    const int wave = tid >> 6, lane = tid & 63, quad = lane >> 4, l15 = lane & 15;
    const int id = blockIdx.x;
    const int ibk = id >> 6;
    const int bh = (id & 63) >> 1;
    const int js = id & 1;
    const int b = bh >> 3, h = bh & 7;
    const int i0 = ibk * 256 + wave * 64;
    const int jbase = js * (Nc / 2);
    const ushort_t* Q  = q  + ((size_t)bh * Nc + i0) * DKc;
    const ushort_t* Kb = k  + (size_t)bh * Nc * DKc;
    const ushort_t* Vb = vT + (size_t)bh * DKc * Nc;
    ushort_t* Pw = Ps[wave];
    const int sw = l15 & 7;
    const int hb = (l15 >> 3) & 1;

    sh8 bQ[4][2];
#pragma unroll
    for (int ni = 0; ni < 4; ++ni)
#pragma unroll
        for (int kk = 0; kk < 2; ++kk)
            bQ[ni][kk] = *(const sh8*)&Q[(size_t)(ni * 16 + l15) * DKc + kk * 32 + quad * 8];

    f4 acc[4][4];
#pragma unroll
    for (int i = 0; i < 4; ++i)
#pragma unroll
        for (int j = 0; j < 4; ++j) acc[i][j] = (f4)0.f;

    int koff[4], voff[4], lbase[4];
#pragma unroll
    for (int c = 0; c < 4; ++c) {
        int g = c * 256 + tid;
        int rk = g >> 3, ck = (g & 7) ^ (rk & 7);
        koff[c] = rk * DKc + ck * 8;
        int rv = g >> 4, cs = g & 15, cn = (cs & 8) | ((cs & 7) ^ (rv & 7));
        voff[c] = rv * Nc + cn * 8;
        lbase[c] = (c * 256 + wave * 64) * 8;
    }

    for (int st = 0; st < 8; ++st) {
        const int j0 = jbase + st * 128;
#pragma unroll
        for (int c = 0; c < 4; ++c) {
            gl_lds16(Kb + (size_t)j0 * DKc + koff[c], Ks + lbase[c]);
            gl_lds16(Vb + voff[c] + j0,               Vs + lbase[c]);
        }
        __syncthreads();

#pragma unroll
        for (int jj = 0; jj < 128; jj += 64) {
            sh8 aK[4][2];
#pragma unroll
            for (int mj = 0; mj < 4; ++mj)
#pragma unroll
                for (int kk = 0; kk < 2; ++kk)
                    aK[mj][kk] = *(const sh8*)&Ks[(jj + mj * 16 + l15) * 64 +
                                                  (((kk * 4 + quad) ^ sw) << 3)];
#pragma unroll
            for (int ni = 0; ni < 4; ++ni) {
                const int prow = ni * 16 + l15;
#pragma unroll
                for (int mj = 0; mj < 4; ++mj) {
                    f4 s = (f4)0.f;
                    s = __builtin_amdgcn_mfma_f32_16x16x32_bf16(aK[mj][0], bQ[ni][0], s, 0, 0, 0);
                    s = __builtin_amdgcn_mfma_f32_16x16x32_bf16(aK[mj][1], bQ[ni][1], s, 0, 0, 0);
                    const int e0 = fexp2_bf(s[0]);
                    const int e1 = fexp2_bf(s[1]);
                    const int e2 = fexp2_bf(s[2]);
                    const int e3 = fexp2_bf(s[3]);
                    uint2 pk;
                    pk.x = __builtin_amdgcn_perm((unsigned)e1, (unsigned)e0, 0x05040100u);
                    pk.y = __builtin_amdgcn_perm((unsigned)e3, (unsigned)e2, 0x05040100u);
                    const int off = prow * 64 + ((((mj * 2 + (quad >> 1)) ^ sw)) << 3)
                                  + (((quad & 1) ^ hb) << 2);
                    *(uint2*)&Pw[off] = pk;
                }
            }
#pragma unroll
            for (int kk = 0; kk < 2; ++kk) {
                const int cgk = (((kk * 4 + quad) ^ sw)) << 3;
                const int h0 = hb << 2, h1 = 4 - h0;
                sh8 aP[4], bV[4];
#pragma unroll
                for (int mi = 0; mi < 4; ++mi) {
                    union { sh8 s8; uint2 u[2]; } t;
                    const int rb = (mi * 16 + l15) * 64 + cgk;
                    t.u[0] = *(const uint2*)&Pw[rb + h0];
                    t.u[1] = *(const uint2*)&Pw[rb + h1];
                    aP[mi] = t.s8;
                }
                const int gnat = (jj >> 3) + kk * 4 + quad;
                const int vcg = ((gnat & 8) | ((gnat & 7) ^ sw)) << 3;
#pragma unroll
                for (int nd = 0; nd < 4; ++nd)
                    bV[nd] = *(const sh8*)&Vs[(nd * 16 + l15) * 128 + vcg];
#pragma unroll
                for (int mi = 0; mi < 4; ++mi)
#pragma unroll
                    for (int nd = 0; nd < 4; ++nd)
                        acc[mi][nd] = __builtin_amdgcn_mfma_f32_16x16x32_bf16(
                            aP[mi], bV[nd], acc[mi][nd], 0, 0, 0);
            }
        }
        __syncthreads();
    }

    ushort_t* part = js ? part1 : part0;
    ushort_t* dst = part + ((size_t)b * Nc + i0) * Cc + h * DKc;
#pragma unroll
    for (int mi = 0; mi < 4; ++mi)
#pragma unroll
        for (int nd = 0; nd < 4; ++nd)
#pragma unroll
            for (int r = 0; r < 4; ++r)
                dst[(size_t)(mi * 16 + quad * 4 + r) * Cc + nd * 16 + l15] =
                    f2bf(acc[mi][nd][r]);
}

// res (== part1 in-place) = bf16( fp32(part0) + fp32(part1) )
__global__ __launch_bounds__(256) void reduce_kernel(
    const ushort_t* __restrict__ p0, ushort_t* __restrict__ p1res)
{
    int i = blockIdx.x * 256 + threadIdx.x;
    us4 a = ((const us4*)p0)[i];
    us4 b = ((const us4*)p1res)[i];
    us4 o;
#pragma unroll
    for (int j = 0; j < 4; ++j)
        o[j] = f2bf(bf2f(a[j]) + bf2f(b[j]));
    ((us4*)p1res)[i] = o;
}

// ---------------------------------------------------------------------------
// Kernel 4: out[b,co,n] = res @ Wo^T + bo + x  (R6 version)
// ---------------------------------------------------------------------------
__global__ __launch_bounds__(256) void out_kernel(
    const ushort_t* __restrict__ res, const ushort_t* __restrict__ Wob,
    const float* __restrict__ bo, const float* __restrict__ x,
    float* __restrict__ out)
{
    const int tid = threadIdx.x;
    const int wave = tid >> 6, lane = tid & 63, quad = lane >> 4, l15 = lane & 15;
    const int m0  = blockIdx.x * 128 + (wave & 1) * 64;
    const int co0 = blockIdx.y * 128 + (wave >> 1) * 64;
    const ushort_t* A  = res + (size_t)m0 * Cc;
    const ushort_t* Bw = Wob + (size_t)co0 * Cc;

    f4 acc[4][4];
#pragma unroll
    for (int i = 0; i < 4; ++i)
#pragma unroll
        for (int j = 0; j < 4; ++j) acc[i][j] = (f4)0.f;

    for (int kk = 0; kk < Cc; kk += 32) {
        sh8 a[4], bb[4];
#pragma unroll
        for (int mi = 0; mi < 4; ++mi)
            a[mi] = *(const sh8*)&A[(size_t)(mi * 16 + l15) * Cc + kk + quad * 8];
#pragma unroll
        for (int ni = 0; ni < 4; ++ni)
            bb[ni] = *(const sh8*)&Bw[(size_t)(ni * 16 + l15) * Cc + kk + quad * 8];
#pragma unroll
        for (int mi = 0; mi < 4; ++mi)
#pragma unroll
            for (int ni = 0; ni < 4; ++ni)
                acc[mi][ni] = __builtin_amdgcn_mfma_f32_16x16x32_bf16(
                    a[mi], bb[ni], acc[mi][ni], 0, 0, 0);
    }

    const int b = m0 >> 11;
    const int n_base = m0 & 2047;
#pragma unroll
    for (int ni = 0; ni < 4; ++ni) {
        const int co = co0 + ni * 16 + l15;
        const float bias = bo[co];
#pragma unroll
        for (int mi = 0; mi < 4; ++mi) {
            const int n = n_base + mi * 16 + quad * 4;
            const size_t idx = ((size_t)b * Cc + co) * Nc + n;
            float4 xr = *(const float4*)&x[idx];
            float4 o;
            o.x = acc[mi][ni][0] + bias + xr.x;
            o.y = acc[mi][ni][1] + bias + xr.y;
            o.z = acc[mi][ni][2] + bias + xr.z;
            o.w = acc[mi][ni][3] + bias + xr.w;
            *(float4*)&out[idx] = o;
        }
    }
}

// ---------------------------------------------------------------------------
extern "C" void kernel_launch(void* const* d_in, const int* in_sizes, int n_in,
                              void* d_out, int out_size, void* d_ws, size_t ws_size,
                              hipStream_t stream)
{
    const float* x  = (const float*)d_in[0];
    const float* Wp = (const float*)d_in[1];
    const float* bp = (const float*)d_in[2];
    const float* Wo = (const float*)d_in[3];
    const float* bo = (const float*)d_in[4];
    float* out = (float*)d_out;

    float* coef  = (float*)d_ws;                              // unused slot
    float* spart = coef + BHN;                                // NSPLIT_S * BHN
    ushort_t* wsb = (ushort_t*)(spart + (size_t)NSPLIT_S * BHN);
    const size_t nE = (size_t)Bc * Nc * Cc;                   // 4,194,304
    ushort_t* xt  = wsb;                 // also part0 (dead after qkv)
    ushort_t* Wpb = xt  + nE;
    ushort_t* Wob = Wpb + (size_t)O3c * Cc;
    ushort_t* qw  = Wob + (size_t)Cc * Cc;
    ushort_t* kw  = qw + nE;
    ushort_t* vT  = kw + nE;
    ushort_t* res = vT + nE;             // also part1

    xpose_kernel<<<dim3(Nc / 32, Cc / 32, Bc), 256, 0, stream>>>(x, xt);
    cvt_kernel<<<dim3((O3c * Cc / 4 + 255) / 256), 256, 0, stream>>>(Wp, Wpb, O3c * Cc / 4);
    cvt_kernel<<<dim3((Cc * Cc / 4 + 255) / 256), 256, 0, stream>>>(Wo, Wob, Cc * Cc / 4);
    qkv_kernel<<<dim3(O3c / 128, Nc / 128, Bc), 256, 0, stream>>>(xt, Wpb, bp, qw, kw, vT);
    stats_kernel<<<dim3(512), 256, 0, stream>>>(qw, kw, spart);
    vscale_kernel<<<dim3((int)(nE / 4 / 256)), 256, 0, stream>>>(vT, spart);
    apply_kernel<<<dim3(512), 256, 0, stream>>>(qw, kw, vT, xt, res);
    reduce_kernel<<<dim3((int)(nE / 4 / 256)), 256, 0, stream>>>(xt, res);
    out_kernel<<<dim3(Bc * Nc / 128, Cc / 128), 256, 0, stream>>>(res, Wob, bo, x, out);
}

// Round 10
// 200.203 us; speedup vs baseline: 1.3291x; 1.0119x over previous
//
#include <hip/hip_runtime.h>
#include <cstddef>

typedef unsigned short ushort_t;
typedef __attribute__((ext_vector_type(8))) short sh8;   // 8 x bf16 bits = 4 VGPRs
typedef __attribute__((ext_vector_type(4))) float f4;    // MFMA 16x16x32 C/D
typedef __attribute__((ext_vector_type(4))) unsigned short us4;

static constexpr int Bc = 4, Cc = 512, Nc = 2048, Hc = 8, DKc = 64, O3c = 1536;
static constexpr int BHN = Bc * Hc * Nc;               // 65536
static constexpr int NSPLIT_S = 4;                     // stats i-split
static constexpr float K2 = 0.125f * 1.44269504089f;   // scale * log2(e), folded into q

__device__ __forceinline__ unsigned short f2bf(float f) {
    union { float f; unsigned u; } v; v.f = f;
    unsigned r = v.u + 0x7FFFu + ((v.u >> 16) & 1u);  // RNE
    return (unsigned short)(r >> 16);
}
__device__ __forceinline__ float bf2f(unsigned short b) {
    union { unsigned u; float f; } v; v.u = ((unsigned)b) << 16;
    return v.f;
}
__device__ __forceinline__ float ubf(unsigned u) {
    union { unsigned u; float f; } v; v.u = u; return v.f;
}
// Schraudolph fast 2^s (linear mantissa, deficit <=5.7%) — used in BOTH
// stats (denominator) and apply (numerator) so the softmax ratio cancels.
__device__ __forceinline__ float fexp2(float s) {
    return ubf((unsigned)(int)fmaf(s, 8388608.0f, 1065353216.0f));
}
__device__ __forceinline__ int fexp2_bf(float s) {
    return (int)fmaf(s, 128.0f, 16256.5f);
}
__device__ __forceinline__ void gl_lds16(const ushort_t* g, ushort_t* l) {
    __builtin_amdgcn_global_load_lds(
        (const __attribute__((address_space(1))) unsigned int*)g,
        (__attribute__((address_space(3))) unsigned int*)l, 16, 0, 0);
}

// ---------------------------------------------------------------------------
// Prep A: x[b,c,n] fp32 -> xt[b,n,c] bf16
// ---------------------------------------------------------------------------
__global__ __launch_bounds__(256) void xpose_kernel(
    const float* __restrict__ x, ushort_t* __restrict__ xt)
{
    __shared__ float t[32][33];
    const int b = blockIdx.z, n0 = blockIdx.x * 32, c0 = blockIdx.y * 32;
    const int tx = threadIdx.x & 31, ty = threadIdx.x >> 5;
    const float* xb = x + (size_t)b * Cc * Nc;
#pragma unroll
    for (int r = 0; r < 4; ++r)
        t[ty + r * 8][tx] = xb[(size_t)(c0 + ty + r * 8) * Nc + n0 + tx];
    __syncthreads();
    ushort_t* xtb = xt + (size_t)b * Nc * Cc;
#pragma unroll
    for (int r = 0; r < 4; ++r)
        xtb[(size_t)(n0 + ty + r * 8) * Cc + c0 + tx] = f2bf(t[tx][ty + r * 8]);
}

// ---------------------------------------------------------------------------
// Prep B: both weight converts in one launch. Wpb and Wob are contiguous in
// the workspace, so dst is a single flat array.
// ---------------------------------------------------------------------------
__global__ __launch_bounds__(256) void cvt2_kernel(
    const float* __restrict__ s1, const float* __restrict__ s2,
    ushort_t* __restrict__ d, int n4a, int n4tot)
{
    int i = blockIdx.x * 256 + threadIdx.x;
    if (i >= n4tot) return;
    float4 v = (i < n4a) ? ((const float4*)s1)[i] : ((const float4*)s2)[i - n4a];
    us4 o = { f2bf(v.x), f2bf(v.y), f2bf(v.z), f2bf(v.w) };
    ((us4*)d)[i] = o;
}

// ---------------------------------------------------------------------------
// Kernel 1: qkv projection, m97-style LDS-staged GEMM (R9 version; passed).
// ---------------------------------------------------------------------------
__global__ __launch_bounds__(256, 2) void qkv_kernel(
    const ushort_t* __restrict__ xt, const ushort_t* __restrict__ Wpb,
    const float* __restrict__ bp,
    ushort_t* __restrict__ q, ushort_t* __restrict__ k, ushort_t* __restrict__ vT)
{
    __shared__ __align__(16) ushort_t As[128 * 64];   // 16 KB
    __shared__ __align__(16) ushort_t Bs[128 * 64];   // 16 KB
    const int tid = threadIdx.x;
    const int wave = tid >> 6, lane = tid & 63, quad = lane >> 4, l15 = lane & 15;
    const int b = blockIdx.z;
    const int t0  = blockIdx.y * 128;
    const int o0b = blockIdx.x * 128;
    const int wt = wave & 1, wo = wave >> 1;
    const int m0 = t0 + wt * 64;
    const int o0 = o0b + wo * 64;
    const ushort_t* Ag = xt  + ((size_t)b * Nc + t0) * Cc;
    const ushort_t* Bg = Wpb + (size_t)o0b * Cc;
    const int f  = (o0 >> 6) % 3;
    const int h  = o0 / 192;
    const int bh = b * Hc + h;
    const int sw = l15 & 7;

    f4 acc[4][4];
#pragma unroll
    for (int i = 0; i < 4; ++i)
#pragma unroll
        for (int j = 0; j < 4; ++j) acc[i][j] = (f4)0.f;

    int goff[4], lbase[4];
#pragma unroll
    for (int c = 0; c < 4; ++c) {
        int g = c * 256 + tid;
        int r = g >> 3, cn = (g & 7) ^ (r & 7);
        goff[c]  = r * Cc + cn * 8;
        lbase[c] = (c * 256 + wave * 64) * 8;
    }

    for (int st = 0; st < 8; ++st) {
        const int k0 = st * 64;
#pragma unroll
        for (int c = 0; c < 4; ++c) {
            gl_lds16(Ag + k0 + goff[c], As + lbase[c]);
            gl_lds16(Bg + k0 + goff[c], Bs + lbase[c]);
        }
        __syncthreads();

        sh8 aA[4][2], bB[4][2];
#pragma unroll
        for (int mi = 0; mi < 4; ++mi)
#pragma unroll
            for (int kk = 0; kk < 2; ++kk)
                aA[mi][kk] = *(const sh8*)&As[(wt * 64 + mi * 16 + l15) * 64 +
                                              (((kk * 4 + quad) ^ sw) << 3)];
#pragma unroll
        for (int ni = 0; ni < 4; ++ni)
#pragma unroll
            for (int kk = 0; kk < 2; ++kk)
                bB[ni][kk] = *(const sh8*)&Bs[(wo * 64 + ni * 16 + l15) * 64 +
                                              (((kk * 4 + quad) ^ sw) << 3)];
        if (f == 2) {
#pragma unroll
            for (int kk = 0; kk < 2; ++kk)
#pragma unroll
                for (int mi = 0; mi < 4; ++mi)
#pragma unroll
                    for (int ni = 0; ni < 4; ++ni)
                        acc[mi][ni] = __builtin_amdgcn_mfma_f32_16x16x32_bf16(
                            aA[mi][kk], bB[ni][kk], acc[mi][ni], 0, 0, 0);
        } else {
#pragma unroll
            for (int kk = 0; kk < 2; ++kk)
#pragma unroll
                for (int mo = 0; mo < 4; ++mo)
#pragma unroll
                    for (int nt = 0; nt < 4; ++nt)
                        acc[mo][nt] = __builtin_amdgcn_mfma_f32_16x16x32_bf16(
                            bB[mo][kk], aA[nt][kk], acc[mo][nt], 0, 0, 0);
        }
        __syncthreads();
    }

    if (f == 2) {
#pragma unroll
        for (int ni = 0; ni < 4; ++ni) {
            const int o = o0 + ni * 16 + l15;
            const int d = o & 63;
            const float bias = bp[o];
            ushort_t* dst = vT + ((size_t)bh * DKc + d) * Nc + m0;
#pragma unroll
            for (int mi = 0; mi < 4; ++mi) {
                us4 pk = { f2bf(acc[mi][ni][0] + bias), f2bf(acc[mi][ni][1] + bias),
                           f2bf(acc[mi][ni][2] + bias), f2bf(acc[mi][ni][3] + bias) };
                *(us4*)&dst[mi * 16 + quad * 4] = pk;
            }
        }
    } else {
        const float qs = (f == 0) ? K2 : 1.0f;
        ushort_t* dst = (f == 0 ? q : k) + (size_t)bh * Nc * DKc;
#pragma unroll
        for (int mo = 0; mo < 4; ++mo) {
            const int d0 = mo * 16 + quad * 4;
            const float4 b4 = *(const float4*)&bp[o0 + d0];
#pragma unroll
            for (int nt = 0; nt < 4; ++nt) {
                const int token = m0 + nt * 16 + l15;
                us4 pk = { f2bf((acc[mo][nt][0] + b4.x) * qs),
                           f2bf((acc[mo][nt][1] + b4.y) * qs),
                           f2bf((acc[mo][nt][2] + b4.z) * qs),
                           f2bf((acc[mo][nt][3] + b4.w) * qs) };
                *(us4*)&dst[(size_t)token * DKc + d0] = pk;
            }
        }
    }
}

// ---------------------------------------------------------------------------
// Kernel 2: partial column sums, 4-way i-split, 4 blocks/CU.
// id = jb*128 + bh*4 + is (XCD-affine in (bh,is)).
// ---------------------------------------------------------------------------
__global__ __launch_bounds__(256, 4) void stats_kernel(
    const ushort_t* __restrict__ q, const ushort_t* __restrict__ k,
    float* __restrict__ spart)
{
    const int tid = threadIdx.x;
    const int wave = tid >> 6, lane = tid & 63, quad = lane >> 4, l15 = lane & 15;
    const int id = blockIdx.x;
    const int jb = id >> 7;
    const int bh = (id >> 2) & 31;
    const int is = id & 3;
    const int j0 = jb * 256 + wave * 64;
    const int ibase = is * (Nc / NSPLIT_S);
    const ushort_t* K = k + ((size_t)bh * Nc + j0) * DKc;
    const ushort_t* Q = q + (size_t)bh * Nc * DKc;

    sh8 aK[4][2];
#pragma unroll
    for (int mj = 0; mj < 4; ++mj)
#pragma unroll
        for (int kk = 0; kk < 2; ++kk)
            aK[mj][kk] = *(const sh8*)&K[(size_t)(mj * 16 + l15) * DKc + kk * 32 + quad * 8];

    float lsum[4][4] = {};
    for (int it = 0; it < Nc / NSPLIT_S; it += 64) {
        const int i0 = ibase + it;
        sh8 bQ[4][2];
#pragma unroll
        for (int ni = 0; ni < 4; ++ni)
#pragma unroll
            for (int kk = 0; kk < 2; ++kk)
                bQ[ni][kk] = *(const sh8*)&Q[(size_t)(i0 + ni * 16 + l15) * DKc + kk * 32 + quad * 8];
#pragma unroll
        for (int mj = 0; mj < 4; ++mj)
#pragma unroll
            for (int ni = 0; ni < 4; ++ni) {
                f4 s = (f4)0.f;
                s = __builtin_amdgcn_mfma_f32_16x16x32_bf16(aK[mj][0], bQ[ni][0], s, 0, 0, 0);
                s = __builtin_amdgcn_mfma_f32_16x16x32_bf16(aK[mj][1], bQ[ni][1], s, 0, 0, 0);
#pragma unroll
                for (int r = 0; r < 4; ++r)
                    lsum[mj][r] += fexp2(s[r]);
            }
    }
#pragma unroll
    for (int mj = 0; mj < 4; ++mj)
#pragma unroll
        for (int r = 0; r < 4; ++r) {
            float v = lsum[mj][r];
            v += __shfl_xor(v, 1); v += __shfl_xor(v, 2);
            v += __shfl_xor(v, 4); v += __shfl_xor(v, 8);
            if (l15 == 0)
                spart[((size_t)is * Bc * Hc + bh) * Nc + j0 + mj * 16 + quad * 4 + r] = v;
        }
}

// vT[bh,d,j] *= 1/sum_is spart[is][bh,j]
__global__ __launch_bounds__(256) void vscale_kernel(
    ushort_t* __restrict__ vT, const float* __restrict__ spart)
{
    int i = blockIdx.x * 256 + threadIdx.x;   // us4 index
    int f = i * 4;
    int row = f >> 11;                        // bh*64 + d
    int j = f & 2047;
    int bh = row >> 6;
    const float* sp = spart + (size_t)bh * Nc + j;
    float4 s0 = *(const float4*)sp;
    float4 s1 = *(const float4*)(sp + BHN);
    float4 s2 = *(const float4*)(sp + 2 * BHN);
    float4 s3 = *(const float4*)(sp + 3 * BHN);
    float4 t = { s0.x + s1.x + s2.x + s3.x, s0.y + s1.y + s2.y + s3.y,
                 s0.z + s1.z + s2.z + s3.z, s0.w + s1.w + s2.w + s3.w };
    us4 v = ((us4*)vT)[i];
    us4 o = { f2bf(bf2f(v[0]) / t.x), f2bf(bf2f(v[1]) / t.y),
              f2bf(bf2f(v[2]) / t.z), f2bf(bf2f(v[3]) / t.w) };
    ((us4*)vT)[i] = o;
}

// ---------------------------------------------------------------------------
// Kernel 3: partial PV (R8/R9 version with fast bf16 exp2; passed).
// ---------------------------------------------------------------------------
__global__ __launch_bounds__(256, 2) void apply_kernel(
    const ushort_t* __restrict__ q, const ushort_t* __restrict__ k,
    const ushort_t* __restrict__ vT,
    ushort_t* __restrict__ part0, ushort_t* __restrict__ part1)
{
    __shared__ __align__(16) ushort_t Ks[128 * 64];     // 16 KB
    __shared__ __align__(16) ushort_t Vs[64 * 128];     // 16 KB
    __shared__ __align__(16) ushort_t Ps[4][64 * 64];   // 32 KB per-wave
    const int tid = threadIdx.x;
    const int wave = tid >> 6, lane = tid & 63, quad = lane >> 4, l15 = lane & 15;
    const int id = blockIdx.x;
    const int ibk = id >> 6;
    const int bh = (id & 63) >> 1;
    const int js = id & 1;
    const int b = bh >> 3, h = bh & 7;
    const int i0 = ibk * 256 + wave * 64;
    const int jbase = js * (Nc / 2);
    const ushort_t* Q  = q  + ((size_t)bh * Nc + i0) * DKc;
    const ushort_t* Kb = k  + (size_t)bh * Nc * DKc;
    const ushort_t* Vb = vT + (size_t)bh * DKc * Nc;
    ushort_t* Pw = Ps[wave];
    const int sw = l15 & 7;
    const int hb = (l15 >> 3) & 1;

    sh8 bQ[4][2];
#pragma unroll
    for (int ni = 0; ni < 4; ++ni)
#pragma unroll
        for (int kk = 0; kk < 2; ++kk)
            bQ[ni][kk] = *(const sh8*)&Q[(size_t)(ni * 16 + l15) * DKc + kk * 32 + quad * 8];

    f4 acc[4][4];
#pragma unroll
    for (int i = 0; i < 4; ++i)
#pragma unroll
        for (int j = 0; j < 4; ++j) acc[i][j] = (f4)0.f;

    int koff[4], voff[4], lbase[4];
#pragma unroll
    for (int c = 0; c < 4; ++c) {
        int g = c * 256 + tid;
        int rk = g >> 3, ck = (g & 7) ^ (rk & 7);
        koff[c] = rk * DKc + ck * 8;
        int rv = g >> 4, cs = g & 15, cn = (cs & 8) | ((cs & 7) ^ (rv & 7));
        voff[c] = rv * Nc + cn * 8;
        lbase[c] = (c * 256 + wave * 64) * 8;
    }

    for (int st = 0; st < 8; ++st) {
        const int j0 = jbase + st * 128;
#pragma unroll
        for (int c = 0; c < 4; ++c) {
            gl_lds16(Kb + (size_t)j0 * DKc + koff[c], Ks + lbase[c]);
            gl_lds16(Vb + voff[c] + j0,               Vs + lbase[c]);
        }
        __syncthreads();

#pragma unroll
        for (int jj = 0; jj < 128; jj += 64) {
            sh8 aK[4][2];
#pragma unroll
            for (int mj = 0; mj < 4; ++mj)
#pragma unroll
                for (int kk = 0; kk < 2; ++kk)
                    aK[mj][kk] = *(const sh8*)&Ks[(jj + mj * 16 + l15) * 64 +
                                                  (((kk * 4 + quad) ^ sw) << 3)];
#pragma unroll
            for (int ni = 0; ni < 4; ++ni) {
                const int prow = ni * 16 + l15;
#pragma unroll
                for (int mj = 0; mj < 4; ++mj) {
                    f4 s = (f4)0.f;
                    s = __builtin_amdgcn_mfma_f32_16x16x32_bf16(aK[mj][0], bQ[ni][0], s, 0, 0, 0);
                    s = __builtin_amdgcn_mfma_f32_16x16x32_bf16(aK[mj][1], bQ[ni][1], s, 0, 0, 0);
                    const int e0 = fexp2_bf(s[0]);
                    const int e1 = fexp2_bf(s[1]);
                    const int e2 = fexp2_bf(s[2]);
                    const int e3 = fexp2_bf(s[3]);
                    uint2 pk;
                    pk.x = __builtin_amdgcn_perm((unsigned)e1, (unsigned)e0, 0x05040100u);
                    pk.y = __builtin_amdgcn_perm((unsigned)e3, (unsigned)e2, 0x05040100u);
                    const int off = prow * 64 + ((((mj * 2 + (quad >> 1)) ^ sw)) << 3)
                                  + (((quad & 1) ^ hb) << 2);
                    *(uint2*)&Pw[off] = pk;
                }
            }
#pragma unroll
            for (int kk = 0; kk < 2; ++kk) {
                const int cgk = (((kk * 4 + quad) ^ sw)) << 3;
                const int h0 = hb << 2, h1 = 4 - h0;
                sh8 aP[4], bV[4];
#pragma unroll
                for (int mi = 0; mi < 4; ++mi) {
                    union { sh8 s8; uint2 u[2]; } t;
                    const int rb = (mi * 16 + l15) * 64 + cgk;
                    t.u[0] = *(const uint2*)&Pw[rb + h0];
                    t.u[1] = *(const uint2*)&Pw[rb + h1];
                    aP[mi] = t.s8;
                }
                const int gnat = (jj >> 3) + kk * 4 + quad;
                const int vcg = ((gnat & 8) | ((gnat & 7) ^ sw)) << 3;
#pragma unroll
                for (int nd = 0; nd < 4; ++nd)
                    bV[nd] = *(const sh8*)&Vs[(nd * 16 + l15) * 128 + vcg];
#pragma unroll
                for (int mi = 0; mi < 4; ++mi)
#pragma unroll
                    for (int nd = 0; nd < 4; ++nd)
                        acc[mi][nd] = __builtin_amdgcn_mfma_f32_16x16x32_bf16(
                            aP[mi], bV[nd], acc[mi][nd], 0, 0, 0);
            }
        }
        __syncthreads();
    }

    ushort_t* part = js ? part1 : part0;
    ushort_t* dst = part + ((size_t)b * Nc + i0) * Cc + h * DKc;
#pragma unroll
    for (int mi = 0; mi < 4; ++mi)
#pragma unroll
        for (int nd = 0; nd < 4; ++nd)
#pragma unroll
            for (int r = 0; r < 4; ++r)
                dst[(size_t)(mi * 16 + quad * 4 + r) * Cc + nd * 16 + l15] =
                    f2bf(acc[mi][nd][r]);
}

// res (== part1 in-place) = bf16( fp32(part0) + fp32(part1) )
__global__ __launch_bounds__(256) void reduce_kernel(
    const ushort_t* __restrict__ p0, ushort_t* __restrict__ p1res)
{
    int i = blockIdx.x * 256 + threadIdx.x;
    us4 a = ((const us4*)p0)[i];
    us4 b = ((const us4*)p1res)[i];
    us4 o;
#pragma unroll
    for (int j = 0; j < 4; ++j)
        o[j] = f2bf(bf2f(a[j]) + bf2f(b[j]));
    ((us4*)p1res)[i] = o;
}

// ---------------------------------------------------------------------------
// Kernel 4: out = res @ Wo^T + bo + x — staged-LDS, tile 128tok x 64co,
// grid 512 -> 2 blocks/CU, 8 waves/CU (was 1 block/CU direct-load).
// ---------------------------------------------------------------------------
__global__ __launch_bounds__(256, 2) void out_kernel(
    const ushort_t* __restrict__ res, const ushort_t* __restrict__ Wob,
    const float* __restrict__ bo, const float* __restrict__ x,
    float* __restrict__ out)
{
    __shared__ __align__(16) ushort_t As[128 * 64];   // 16 KB
    __shared__ __align__(16) ushort_t Bs[64 * 64];    // 8 KB
    const int tid = threadIdx.x;
    const int wave = tid >> 6, lane = tid & 63, quad = lane >> 4, l15 = lane & 15;
    const int wt = wave & 1, wo = wave >> 1;
    const int t0   = blockIdx.x * 128;                // global token base
    const int co0b = blockIdx.y * 64;
    const ushort_t* Ag = res + (size_t)t0 * Cc;
    const ushort_t* Bg = Wob + (size_t)co0b * Cc;
    const int sw = l15 & 7;

    f4 acc[4][2];
#pragma unroll
    for (int i = 0; i < 4; ++i)
#pragma unroll
        for (int j = 0; j < 2; ++j) acc[i][j] = (f4)0.f;

    int goffA[4], lbaseA[4], goffB[2], lbaseB[2];
#pragma unroll
    for (int c = 0; c < 4; ++c) {
        int g = c * 256 + tid;
        int r = g >> 3, cn = (g & 7) ^ (r & 7);
        goffA[c]  = r * Cc + cn * 8;
        lbaseA[c] = (c * 256 + wave * 64) * 8;
    }
#pragma unroll
    for (int c = 0; c < 2; ++c) {
        int g = c * 256 + tid;
        int r = g >> 3, cn = (g & 7) ^ (r & 7);
        goffB[c]  = r * Cc + cn * 8;
        lbaseB[c] = (c * 256 + wave * 64) * 8;
    }

    for (int st = 0; st < 8; ++st) {
        const int k0 = st * 64;
#pragma unroll
        for (int c = 0; c < 4; ++c)
            gl_lds16(Ag + k0 + goffA[c], As + lbaseA[c]);
#pragma unroll
        for (int c = 0; c < 2; ++c)
            gl_lds16(Bg + k0 + goffB[c], Bs + lbaseB[c]);
        __syncthreads();

        sh8 aA[4][2], bB[2][2];
#pragma unroll
        for (int mi = 0; mi < 4; ++mi)
#pragma unroll
            for (int kk = 0; kk < 2; ++kk)
                aA[mi][kk] = *(const sh8*)&As[(wt * 64 + mi * 16 + l15) * 64 +
                                              (((kk * 4 + quad) ^ sw) << 3)];
#pragma unroll
        for (int ni = 0; ni < 2; ++ni)
#pragma unroll
            for (int kk = 0; kk < 2; ++kk)
                bB[ni][kk] = *(const sh8*)&Bs[(wo * 32 + ni * 16 + l15) * 64 +
                                              (((kk * 4 + quad) ^ sw) << 3)];
#pragma unroll
        for (int kk = 0; kk < 2; ++kk)
#pragma unroll
            for (int mi = 0; mi < 4; ++mi)
#pragma unroll
                for (int ni = 0; ni < 2; ++ni)
                    acc[mi][ni] = __builtin_amdgcn_mfma_f32_16x16x32_bf16(
                        aA[mi][kk], bB[ni][kk], acc[mi][ni], 0, 0, 0);
        __syncthreads();
    }

    const int b = t0 >> 11;
    const int n_base = (t0 & 2047) + wt * 64;
#pragma unroll
    for (int ni = 0; ni < 2; ++ni) {
        const int co = co0b + wo * 32 + ni * 16 + l15;
        const float bias = bo[co];
#pragma unroll
        for (int mi = 0; mi < 4; ++mi) {
            const int n = n_base + mi * 16 + quad * 4;
            const size_t idx = ((size_t)b * Cc + co) * Nc + n;
            float4 xr = *(const float4*)&x[idx];
            float4 o;
            o.x = acc[mi][ni][0] + bias + xr.x;
            o.y = acc[mi][ni][1] + bias + xr.y;
            o.z = acc[mi][ni][2] + bias + xr.z;
            o.w = acc[mi][ni][3] + bias + xr.w;
            *(float4*)&out[idx] = o;
        }
    }
}

// ---------------------------------------------------------------------------
extern "C" void kernel_launch(void* const* d_in, const int* in_sizes, int n_in,
                              void* d_out, int out_size, void* d_ws, size_t ws_size,
                              hipStream_t stream)
{
    const float* x  = (const float*)d_in[0];
    const float* Wp = (const float*)d_in[1];
    const float* bp = (const float*)d_in[2];
    const float* Wo = (const float*)d_in[3];
    const float* bo = (const float*)d_in[4];
    float* out = (float*)d_out;

    float* coef  = (float*)d_ws;                              // unused slot (layout kept)
    float* spart = coef + BHN;                                // NSPLIT_S * BHN
    ushort_t* wsb = (ushort_t*)(spart + (size_t)NSPLIT_S * BHN);
    const size_t nE = (size_t)Bc * Nc * Cc;                   // 4,194,304
    ushort_t* xt  = wsb;                 // also part0 (dead after qkv)
    ushort_t* Wpb = xt  + nE;
    ushort_t* Wob = Wpb + (size_t)O3c * Cc;
    ushort_t* qw  = Wob + (size_t)Cc * Cc;
    ushort_t* kw  = qw + nE;
    ushort_t* vT  = kw + nE;
    ushort_t* res = vT + nE;             // also part1

    const int n4a   = O3c * Cc / 4;                 // 196608
    const int n4tot = n4a + Cc * Cc / 4;            // 262144

    xpose_kernel<<<dim3(Nc / 32, Cc / 32, Bc), 256, 0, stream>>>(x, xt);
    cvt2_kernel<<<dim3(n4tot / 256), 256, 0, stream>>>(Wp, Wo, Wpb, n4a, n4tot);
    qkv_kernel<<<dim3(O3c / 128, Nc / 128, Bc), 256, 0, stream>>>(xt, Wpb, bp, qw, kw, vT);
    stats_kernel<<<dim3(1024), 256, 0, stream>>>(qw, kw, spart);
    vscale_kernel<<<dim3((int)(nE / 4 / 256)), 256, 0, stream>>>(vT, spart);
    apply_kernel<<<dim3(512), 256, 0, stream>>>(qw, kw, vT, xt, res);
    reduce_kernel<<<dim3((int)(nE / 4 / 256)), 256, 0, stream>>>(xt, res);
    out_kernel<<<dim3(Bc * Nc / 128, Cc / 64), 256, 0, stream>>>(res, Wob, bo, x, out);
}